// Round 6
// baseline (184.802 us; speedup 1.0000x reference)
//
#include <hip/hip_runtime.h>
#include <hip/hip_bf16.h>

#define H_   4
#define D_   32
#define HD   128   // H*D
#define IND  128
#define OUTD 128
#define NET  3
#define NEG  0.2f
#define CAP  2048  // bucket capacity (expected ~819 edges/bucket, P(>2048) ~ 0)

typedef short short8 __attribute__((ext_vector_type(8)));
typedef float f32x4  __attribute__((ext_vector_type(4)));

__device__ __forceinline__ unsigned short f2bf(float f) {
  union { __hip_bfloat16 b; unsigned short u; } x;
  x.b = __float2bfloat16(f);
  return x.u;
}

// ---------------- K0: fold attn_lin / edge_embed into reduced weights ----------------
// Wred[i][c], c in [0,20): c<4 -> sq(h=c); 4..15 -> qe(t,h); 16..19 -> sk(h)
__global__ void k0_wred(const float* __restrict__ Wq, const float* __restrict__ Wk,
                        const float* __restrict__ attn, const float* __restrict__ ee,
                        float* __restrict__ Wred) {
  int i = threadIdx.x; // 0..127
  for (int h = 0; h < H_; h++) {
    float sq = 0.f, sk = 0.f;
    for (int d = 0; d < D_; d++) {
      sq += Wq[i*HD + h*D_ + d] * attn[h*2*D_ + d];
      sk += Wk[i*HD + h*D_ + d] * attn[h*2*D_ + D_ + d];
    }
    Wred[i*20 + h] = sq;
    Wred[i*20 + 16 + h] = sk;
    for (int t = 0; t < NET; t++) {
      float qe = 0.f;
      for (int d = 0; d < D_; d++)
        qe += Wq[i*HD + h*D_ + d] * ee[t*HD + h*D_ + d];
      Wred[i*20 + 4 + t*4 + h] = qe;
    }
  }
}

// ---------------- K0b: build transposed bf16 weight panels ----------------
__global__ void k0b_pack(const float* __restrict__ Wv, const float* __restrict__ Wred,
                         const float* __restrict__ Wout,
                         unsigned short* __restrict__ Wallt,
                         unsigned short* __restrict__ Woutt) {
  int b = blockIdx.x, i = threadIdx.x; // i = K index
  if (b < 160) {
    int c = b;
    float val = (c < 128) ? Wv[i*HD + c] : (c < 148) ? Wred[i*20 + (c-128)] : 0.f;
    Wallt[c*128 + i] = f2bf(val);
  } else {
    int c = b - 160;
    Woutt[c*128 + i] = f2bf(Wout[i*OUTD + c]);
  }
}

// ---------------- K1: MFMA GEMM  x(n,128) @ [Wv|Wred](128,160) ----------------
// A-tile (64 rows) staged in LDS (16KB); B fragments read from global (L1/L2-hot).
__global__ __launch_bounds__(256) void k1_gemm(const float* __restrict__ x,
    const unsigned short* __restrict__ Wallt,
    unsigned short* __restrict__ vb, float* __restrict__ nq,
    float* __restrict__ skb, int n) {
  __shared__ char lds[16384]; // x-tile [64][128] bf16, XOR-swizzled
  int t = threadIdx.x;
  int base = blockIdx.x * 64;
  #pragma unroll
  for (int it = 0; it < 8; it++) {
    int idx = it*256 + t;           // 2048 float4 = 64x128
    int r = idx >> 5;
    int ch = idx & 31;
    float4 xv = make_float4(0.f, 0.f, 0.f, 0.f);
    if (base + r < n) xv = *(const float4*)(&x[(size_t)(base + r)*IND + ch*4]);
    ushort4 pk = make_ushort4(f2bf(xv.x), f2bf(xv.y), f2bf(xv.z), f2bf(xv.w));
    int byte = (r*256 + ch*8) ^ ((r & 7) << 4);
    *(ushort4*)(lds + byte) = pk;
  }
  __syncthreads();
  int wv = t >> 6, lane = t & 63;
  int l15 = lane & 15, l16 = lane >> 4;
  int arow = wv*16 + l15;
  short8 afr[4];
  #pragma unroll
  for (int kk = 0; kk < 4; kk++) {
    int k0 = kk*32 + l16*8;
    afr[kk] = *(const short8*)(lds + ((arow*256 + k0*2) ^ ((arow & 7) << 4)));
  }
  f32x4 acc[10];
  #pragma unroll
  for (int nt = 0; nt < 10; nt++) acc[nt] = (f32x4){0.f, 0.f, 0.f, 0.f};
  #pragma unroll
  for (int nt = 0; nt < 10; nt++) {
    int bcol = nt*16 + l15;
    #pragma unroll
    for (int kk = 0; kk < 4; kk++) {
      int k0 = kk*32 + l16*8;
      short8 b = *(const short8*)(&Wallt[(size_t)bcol*128 + k0]);
      acc[nt] = __builtin_amdgcn_mfma_f32_16x16x32_bf16(afr[kk], b, acc[nt], 0, 0, 0);
    }
  }
  int rowbase = base + wv*16 + l16*4;
  #pragma unroll
  for (int nt = 0; nt < 10; nt++) {
    int col = nt*16 + l15;
    #pragma unroll
    for (int r = 0; r < 4; r++) {
      int row = rowbase + r;
      if (row >= n) continue;
      float val = acc[nt][r];
      if (nt < 8)       vb[(size_t)row*HD + col] = f2bf(val);
      else if (nt == 8) nq[(size_t)row*16 + (col - 128)] = val;
      else { int c = col - 144; if (c < 4) skb[(size_t)row*4 + c] = val; }
    }
  }
}

// ---------------- K2: two-level bucketed CSR build ----------------
__global__ __launch_bounds__(256) void k_bucket(const int* __restrict__ ei,
    const int* __restrict__ et, int* __restrict__ gbuck,
    unsigned int* __restrict__ ebuf, int E_, int nbuck, int per) {
  __shared__ int cnt[1024];
  __shared__ int base[1024];
  int t = threadIdx.x;
  for (int i = t; i < nbuck; i += 256) cnt[i] = 0;
  __syncthreads();
  int e0 = blockIdx.x * per;
  int e1 = min(e0 + per, E_);
  for (int e = e0 + t; e < e1; e += 256)
    atomicAdd(&cnt[ei[E_ + e] >> 7], 1);
  __syncthreads();
  for (int i = t; i < nbuck; i += 256) {
    int c = cnt[i];
    base[i] = c ? atomicAdd(&gbuck[i], c) : 0;
    cnt[i] = 0;
  }
  __syncthreads();
  for (int e = e0 + t; e < e1; e += 256) {
    int d = ei[E_ + e];
    int b = d >> 7;
    int pos = base[b] + atomicAdd(&cnt[b], 1);
    ebuf[(size_t)b * CAP + pos] =
        (unsigned)ei[e] | ((unsigned)et[e] << 17) | ((unsigned)(d & 127) << 19);
  }
}

__global__ void k_bscan(const int* __restrict__ gbuck, int* __restrict__ bbase,
                        int* __restrict__ offsets, int nbuck, int n, int E_) {
  __shared__ int s[256];
  int t = threadIdx.x;
  int c[4]; int sum = 0;
  #pragma unroll
  for (int k = 0; k < 4; k++) {
    int i = t*4 + k;
    c[k] = (i < nbuck) ? gbuck[i] : 0;
    sum += c[k];
  }
  s[t] = sum; __syncthreads();
  for (int off = 1; off < 256; off <<= 1) {
    int v = (t >= off) ? s[t - off] : 0;
    __syncthreads();
    s[t] += v;
    __syncthreads();
  }
  int run = s[t] - sum;
  #pragma unroll
  for (int k = 0; k < 4; k++) {
    int i = t*4 + k;
    if (i < nbuck) bbase[i] = run;
    run += c[k];
  }
  if (t == 0) offsets[n] = E_;
}

__global__ __launch_bounds__(256) void k_sort(const unsigned int* __restrict__ ebuf,
    const int* __restrict__ gbuck, const int* __restrict__ bbase,
    int* __restrict__ offsets, int* __restrict__ elist, int n) {
  __shared__ int cnt[128], cur[128], sc[128];
  int b = blockIdx.x, t = threadIdx.x;
  int m = gbuck[b];
  int bb = bbase[b];
  if (t < 128) cnt[t] = 0;
  __syncthreads();
  const unsigned int* eb = ebuf + (size_t)b * CAP;
  for (int i = t; i < m; i += 256)
    atomicAdd(&cnt[(eb[i] >> 19) & 127], 1);
  __syncthreads();
  if (t < 128) sc[t] = cnt[t];
  __syncthreads();
  for (int off = 1; off < 128; off <<= 1) {
    int v = (t >= off && t < 128) ? sc[t - off] : 0;
    __syncthreads();
    if (t < 128) sc[t] += v;
    __syncthreads();
  }
  if (t < 128) {
    int excl = sc[t] - cnt[t];
    cur[t] = excl;
    int dst = b * 128 + t;
    if (dst < n) offsets[dst] = bb + excl;
  }
  __syncthreads();
  for (int i = t; i < m; i += 256) {
    unsigned int w = eb[i];
    int dl = (w >> 19) & 127;
    int p = bb + atomicAdd(&cur[dl], 1);
    elist[p] = (int)((w & 0x1FFFFu) | (((w >> 17) & 3u) << 20));
  }
}

// ---------------- K3: 16-lane-group-per-dst softmax + aggregation, bf16 output ----------------
// No max-shift: scores ~N(0,3.4), exp(s) safe in fp32; alpha identical to ref to ~1e-10.
__global__ __launch_bounds__(256) void k3_agg(
    const int* __restrict__ offsets, const int* __restrict__ elist,
    const float* __restrict__ nq, const float* __restrict__ skb,
    const unsigned short* __restrict__ vb, unsigned short* __restrict__ aggb, int n) {
  int t = threadIdx.x;
  int g = t >> 4, s = t & 15;
  int dst = blockIdx.x * 16 + g;
  __shared__ float s_esc[16][17][4];   // [17]: group bank offsets distinct -> no conflicts
  __shared__ int s_src[16][17];
  if (dst >= n) return;
  int off0 = offsets[dst];
  int deg = offsets[dst + 1] - off0;
  int h = s >> 2;                       // head of my 8 dims [s*8 .. s*8+8)
  unsigned short* orow = &aggb[(size_t)dst*HD + s*8];
  if (deg == 0) {
    *(uint4*)orow = make_uint4(0u, 0u, 0u, 0u);
    return;
  }
  float4 sk4 = *(const float4*)(&skb[(size_t)dst*4]);
  float dp0 = 0.f, dp1 = 0.f, dp2 = 0.f, dp3 = 0.f;
  float a0=0.f,a1=0.f,a2=0.f,a3=0.f,a4=0.f,a5=0.f,a6=0.f,a7=0.f;
  for (int bas = 0; bas < deg; bas += 16) {
    int cnt = min(16, deg - bas);
    float e0 = 0.f, e1 = 0.f, e2 = 0.f, e3 = 0.f;
    int src = 0;
    if (s < cnt) {
      int p = elist[off0 + bas + s];
      src = p & 0xFFFFF;
      int ety = p >> 20;
      float4 sq4 = *(const float4*)(&nq[(size_t)src*16]);
      float4 qe4 = *(const float4*)(&nq[(size_t)src*16 + 4 + ety*4]);
      float s0 = sq4.x + sk4.x; s0 = (s0 >= 0.f ? s0 : NEG*s0) + qe4.x; e0 = __expf(s0);
      float s1 = sq4.y + sk4.y; s1 = (s1 >= 0.f ? s1 : NEG*s1) + qe4.y; e1 = __expf(s1);
      float s2 = sq4.z + sk4.z; s2 = (s2 >= 0.f ? s2 : NEG*s2) + qe4.z; e2 = __expf(s2);
      float s3 = sq4.w + sk4.w; s3 = (s3 >= 0.f ? s3 : NEG*s3) + qe4.w; e3 = __expf(s3);
      dp0 += e0; dp1 += e1; dp2 += e2; dp3 += e3;
    }
    s_src[g][s] = src;
    *(float4*)(&s_esc[g][s][0]) = make_float4(e0, e1, e2, e3);
    __builtin_amdgcn_wave_barrier();
    int e = 0;
    for (; e + 2 <= cnt; e += 2) {       // 2 gathers in flight per lane
      float al0 = s_esc[g][e+0][h], al1 = s_esc[g][e+1][h];
      int se0 = s_src[g][e+0], se1 = s_src[g][e+1];
      uint4 v0 = *(const uint4*)(vb + (size_t)se0*HD + s*8);
      uint4 v1 = *(const uint4*)(vb + (size_t)se1*HD + s*8);
      a0 += al0 * __uint_as_float(v0.x << 16);
      a1 += al0 * __uint_as_float(v0.x & 0xFFFF0000u);
      a2 += al0 * __uint_as_float(v0.y << 16);
      a3 += al0 * __uint_as_float(v0.y & 0xFFFF0000u);
      a4 += al0 * __uint_as_float(v0.z << 16);
      a5 += al0 * __uint_as_float(v0.z & 0xFFFF0000u);
      a6 += al0 * __uint_as_float(v0.w << 16);
      a7 += al0 * __uint_as_float(v0.w & 0xFFFF0000u);
      a0 += al1 * __uint_as_float(v1.x << 16);
      a1 += al1 * __uint_as_float(v1.x & 0xFFFF0000u);
      a2 += al1 * __uint_as_float(v1.y << 16);
      a3 += al1 * __uint_as_float(v1.y & 0xFFFF0000u);
      a4 += al1 * __uint_as_float(v1.z << 16);
      a5 += al1 * __uint_as_float(v1.z & 0xFFFF0000u);
      a6 += al1 * __uint_as_float(v1.w << 16);
      a7 += al1 * __uint_as_float(v1.w & 0xFFFF0000u);
    }
    for (; e < cnt; e++) {
      float a = s_esc[g][e][h];
      int se = s_src[g][e];
      uint4 vv = *(const uint4*)(vb + (size_t)se*HD + s*8);
      a0 += a * __uint_as_float(vv.x << 16);
      a1 += a * __uint_as_float(vv.x & 0xFFFF0000u);
      a2 += a * __uint_as_float(vv.y << 16);
      a3 += a * __uint_as_float(vv.y & 0xFFFF0000u);
      a4 += a * __uint_as_float(vv.z << 16);
      a5 += a * __uint_as_float(vv.z & 0xFFFF0000u);
      a6 += a * __uint_as_float(vv.w << 16);
      a7 += a * __uint_as_float(vv.w & 0xFFFF0000u);
    }
    __builtin_amdgcn_wave_barrier();
  }
  #pragma unroll
  for (int off = 1; off < 16; off <<= 1) {
    dp0 += __shfl_xor(dp0, off);
    dp1 += __shfl_xor(dp1, off);
    dp2 += __shfl_xor(dp2, off);
    dp3 += __shfl_xor(dp3, off);
  }
  float den = (h == 0) ? dp0 : (h == 1) ? dp1 : (h == 2) ? dp2 : dp3;
  float inv = 1.f / (den + 1e-10f);
  uint4 pk;
  pk.x = (unsigned)f2bf(a0*inv) | ((unsigned)f2bf(a1*inv) << 16);
  pk.y = (unsigned)f2bf(a2*inv) | ((unsigned)f2bf(a3*inv) << 16);
  pk.z = (unsigned)f2bf(a4*inv) | ((unsigned)f2bf(a5*inv) << 16);
  pk.w = (unsigned)f2bf(a6*inv) | ((unsigned)f2bf(a7*inv) << 16);
  *(uint4*)orow = pk;
}

// ---------------- K4: MFMA GEMM  out = aggb @ Wout + bout ----------------
// A-tile (64 rows bf16) staged in LDS (16KB); B fragments from global.
__global__ __launch_bounds__(256) void k4_gemm(const unsigned short* __restrict__ aggb,
    const unsigned short* __restrict__ Woutt, const float* __restrict__ bout,
    float* __restrict__ out, int n) {
  __shared__ char lds[16384];
  int t = threadIdx.x;
  int base = blockIdx.x * 64;
  #pragma unroll
  for (int it = 0; it < 4; it++) {
    int idx = it*256 + t;           // 1024 uint4 = 64x128 bf16
    int r = idx >> 4;
    int c = idx & 15;
    uint4 v = make_uint4(0u, 0u, 0u, 0u);
    if (base + r < n) v = *(const uint4*)(&aggb[(size_t)(base + r)*HD + c*8]);
    int byte = (r*256 + c*16) ^ ((r & 7) << 4);
    *(uint4*)(lds + byte) = v;
  }
  __syncthreads();
  int wv = t >> 6, lane = t & 63;
  int l15 = lane & 15, l16 = lane >> 4;
  int arow = wv*16 + l15;
  short8 afr[4];
  #pragma unroll
  for (int kk = 0; kk < 4; kk++) {
    int k0 = kk*32 + l16*8;
    afr[kk] = *(const short8*)(lds + ((arow*256 + k0*2) ^ ((arow & 7) << 4)));
  }
  f32x4 acc[8];
  #pragma unroll
  for (int nt = 0; nt < 8; nt++) acc[nt] = (f32x4){0.f, 0.f, 0.f, 0.f};
  #pragma unroll
  for (int nt = 0; nt < 8; nt++) {
    int bcol = nt*16 + l15;
    #pragma unroll
    for (int kk = 0; kk < 4; kk++) {
      int k0 = kk*32 + l16*8;
      short8 b = *(const short8*)(&Woutt[(size_t)bcol*128 + k0]);
      acc[nt] = __builtin_amdgcn_mfma_f32_16x16x32_bf16(afr[kk], b, acc[nt], 0, 0, 0);
    }
  }
  int rowbase = base + wv*16 + l16*4;
  #pragma unroll
  for (int nt = 0; nt < 8; nt++) {
    int col = nt*16 + l15;
    float bv = bout[col];
    #pragma unroll
    for (int r = 0; r < 4; r++) {
      int row = rowbase + r;
      if (row < n) out[(size_t)row*OUTD + col] = acc[nt][r] + bv;
    }
  }
}

extern "C" void kernel_launch(void* const* d_in, const int* in_sizes, int n_in,
                              void* d_out, int out_size, void* d_ws, size_t ws_size,
                              hipStream_t stream) {
  const float* x    = (const float*)d_in[0];
  const float* Wq   = (const float*)d_in[1];
  const float* Wk   = (const float*)d_in[2];
  const float* Wv   = (const float*)d_in[3];
  const float* attn = (const float*)d_in[4];
  const float* ee   = (const float*)d_in[5];
  const float* Wout = (const float*)d_in[6];
  const float* bout = (const float*)d_in[7];
  const int*   ei   = (const int*)d_in[8];
  const int*   et   = (const int*)d_in[9];
  int n  = in_sizes[0] / IND;
  int E_ = in_sizes[9];
  float* out = (float*)d_out;
  int nbuck = (n + 127) >> 7;

  char* w = (char*)d_ws;
  auto alloc = [&](size_t bytes) {
    char* p = w;
    w += (bytes + 255) & ~(size_t)255;
    return p;
  };
  unsigned short* vb    = (unsigned short*)alloc((size_t)n * HD * 2);
  unsigned short* aggb  = (unsigned short*)alloc((size_t)n * HD * 2);
  float* nq       = (float*)alloc((size_t)n * 16 * 4);
  float* skb      = (float*)alloc((size_t)n * 4 * 4);
  float* Wred     = (float*)alloc(128 * 20 * 4);
  unsigned short* Wallt = (unsigned short*)alloc(160 * 128 * 2);
  unsigned short* Woutt = (unsigned short*)alloc(128 * 128 * 2);
  unsigned int* ebuf = (unsigned int*)alloc((size_t)nbuck * CAP * 4);
  int*   gbuck    = (int*)alloc((size_t)nbuck * 4);
  int*   bbase    = (int*)alloc((size_t)nbuck * 4);
  int*   offsets  = (int*)alloc(((size_t)n + 1) * 4);
  int*   elist    = (int*)alloc((size_t)E_ * 4);

  hipMemsetAsync(gbuck, 0, (size_t)nbuck * 4, stream);
  k0_wred<<<1, 128, 0, stream>>>(Wq, Wk, attn, ee, Wred);
  k0b_pack<<<288, 128, 0, stream>>>(Wv, Wred, Wout, Wallt, Woutt);
  k1_gemm<<<(n + 63)/64, 256, 0, stream>>>(x, Wallt, vb, nq, skb, n);
  int per = (E_ + 127) / 128;
  k_bucket<<<128, 256, 0, stream>>>(ei, et, gbuck, ebuf, E_, nbuck, per);
  k_bscan<<<1, 256, 0, stream>>>(gbuck, bbase, offsets, nbuck, n, E_);
  k_sort<<<nbuck, 256, 0, stream>>>(ebuf, gbuck, bbase, offsets, elist, n);
  k3_agg<<<(n + 15)/16, 256, 0, stream>>>(offsets, elist, nq, skb, vb, aggb, n);
  k4_gemm<<<(n + 63)/64, 256, 0, stream>>>(aggb, Woutt, bout, out, n);
}

// Round 7
// 130.068 us; speedup vs baseline: 1.4208x; 1.4208x over previous
//
#include <hip/hip_runtime.h>
#include <hip/hip_bf16.h>

#define H_   4
#define D_   32
#define HD   128   // H*D
#define IND  128
#define OUTD 128
#define NET  3
#define NEG  0.2f
#define CAP  2048  // bucket capacity (expected ~819 edges/bucket, P(>2048) ~ 0)

typedef short short8 __attribute__((ext_vector_type(8)));
typedef float f32x4  __attribute__((ext_vector_type(4)));

__device__ __forceinline__ unsigned short f2bf(float f) {
  union { __hip_bfloat16 b; unsigned short u; } x;
  x.b = __float2bfloat16(f);
  return x.u;
}

__device__ __forceinline__ short8 pack_bf8(float4 lo, float4 hi) {
  union { short8 s; unsigned short u[8]; } r;
  r.u[0] = f2bf(lo.x); r.u[1] = f2bf(lo.y); r.u[2] = f2bf(lo.z); r.u[3] = f2bf(lo.w);
  r.u[4] = f2bf(hi.x); r.u[5] = f2bf(hi.y); r.u[6] = f2bf(hi.z); r.u[7] = f2bf(hi.w);
  return r.s;
}

// ---------------- K0: fold attn_lin / edge_embed into reduced weights ----------------
// Wred[i][c], c in [0,20): c<4 -> sq(h=c); 4..15 -> qe(t,h); 16..19 -> sk(h)
__global__ void k0_wred(const float* __restrict__ Wq, const float* __restrict__ Wk,
                        const float* __restrict__ attn, const float* __restrict__ ee,
                        float* __restrict__ Wred) {
  int i = threadIdx.x; // 0..127
  for (int h = 0; h < H_; h++) {
    float sq = 0.f, sk = 0.f;
    for (int d = 0; d < D_; d++) {
      sq += Wq[i*HD + h*D_ + d] * attn[h*2*D_ + d];
      sk += Wk[i*HD + h*D_ + d] * attn[h*2*D_ + D_ + d];
    }
    Wred[i*20 + h] = sq;
    Wred[i*20 + 16 + h] = sk;
    for (int t = 0; t < NET; t++) {
      float qe = 0.f;
      for (int d = 0; d < D_; d++)
        qe += Wq[i*HD + h*D_ + d] * ee[t*HD + h*D_ + d];
      Wred[i*20 + 4 + t*4 + h] = qe;
    }
  }
}

// ---------------- K0b: build PRE-SWIZZLED transposed bf16 weight panels ----------------
// Logical Wallt[c][i] (c=out col 0..159, i=K 0..127) stored at ushort index
// (c*128+i) ^ ((c&7)<<3), so a LINEAR copy into LDS yields the XOR-swizzled
// layout that makes B-fragment ds_read_b128 conflict-free.
__global__ void k0b_pack(const float* __restrict__ Wv, const float* __restrict__ Wred,
                         const float* __restrict__ Wout,
                         unsigned short* __restrict__ Wallt,
                         unsigned short* __restrict__ Woutt) {
  int b = blockIdx.x, i = threadIdx.x; // i = K index
  if (b < 160) {
    int c = b;
    float val = (c < 128) ? Wv[i*HD + c] : (c < 148) ? Wred[i*20 + (c-128)] : 0.f;
    Wallt[(c*128 + i) ^ ((c & 7) << 3)] = f2bf(val);
  } else {
    int c = b - 160;
    Woutt[(c*128 + i) ^ ((c & 7) << 3)] = f2bf(Wout[i*OUTD + c]);
  }
}

// ---------------- K1: MFMA GEMM  x(n,128) @ [Wv|Wred](128,160) ----------------
// LDS holds ONLY B (40KB, linear copy of pre-swizzled panel) -> 4 blocks/CU.
// A fragments load global->VGPR directly (each 64B line touched once).
__global__ __launch_bounds__(256) void k1_gemm(const float* __restrict__ x,
    const uint4* __restrict__ Wallt,
    unsigned short* __restrict__ vb, float* __restrict__ nq,
    float* __restrict__ skb, int n) {
  __shared__ uint4 ldsB[2560]; // 40KB
  int t = threadIdx.x;
  #pragma unroll
  for (int i = 0; i < 10; i++) ldsB[i*256 + t] = Wallt[i*256 + t];
  int wv = t >> 6, lane = t & 63;
  int l15 = lane & 15, l16 = lane >> 4;
  int base = blockIdx.x * 64;
  int arow = base + wv*16 + l15;
  int rr = min(arow, n - 1);
  const float* xr = &x[(size_t)rr*IND + l16*8];
  short8 afr[4];
  #pragma unroll
  for (int kk = 0; kk < 4; kk++) {
    float4 lo = *(const float4*)(xr + kk*32);
    float4 hi = *(const float4*)(xr + kk*32 + 4);
    afr[kk] = pack_bf8(lo, hi);
  }
  __syncthreads();
  f32x4 acc[10];
  #pragma unroll
  for (int nt = 0; nt < 10; nt++) acc[nt] = (f32x4){0.f, 0.f, 0.f, 0.f};
  #pragma unroll
  for (int nt = 0; nt < 10; nt++) {
    int bcol = nt*16 + l15;
    #pragma unroll
    for (int kk = 0; kk < 4; kk++) {
      int bytec = kk*64 + l16*16;
      short8 b = *(const short8*)((const char*)ldsB + ((bcol*256 + bytec) ^ ((bcol & 7) << 4)));
      acc[nt] = __builtin_amdgcn_mfma_f32_16x16x32_bf16(afr[kk], b, acc[nt], 0, 0, 0);
    }
  }
  int rowbase = base + wv*16 + l16*4;
  #pragma unroll
  for (int nt = 0; nt < 10; nt++) {
    int col = nt*16 + l15;
    #pragma unroll
    for (int r = 0; r < 4; r++) {
      int row = rowbase + r;
      if (row >= n) continue;
      float val = acc[nt][r];
      if (nt < 8)       vb[(size_t)row*HD + col] = f2bf(val);
      else if (nt == 8) nq[(size_t)row*16 + (col - 128)] = val;
      else { int c = col - 144; if (c < 4) skb[(size_t)row*4 + c] = val; }
    }
  }
}

// ---------------- K2: two-level bucketed CSR build ----------------
__global__ __launch_bounds__(256) void k_bucket(const int* __restrict__ ei,
    const int* __restrict__ et, int* __restrict__ gbuck,
    unsigned int* __restrict__ ebuf, int E_, int nbuck, int per) {
  __shared__ int cnt[1024];
  __shared__ int base[1024];
  int t = threadIdx.x;
  for (int i = t; i < nbuck; i += 256) cnt[i] = 0;
  __syncthreads();
  int e0 = blockIdx.x * per;
  int e1 = min(e0 + per, E_);
  for (int e = e0 + t; e < e1; e += 256)
    atomicAdd(&cnt[ei[E_ + e] >> 7], 1);
  __syncthreads();
  for (int i = t; i < nbuck; i += 256) {
    int c = cnt[i];
    base[i] = c ? atomicAdd(&gbuck[i], c) : 0;
    cnt[i] = 0;
  }
  __syncthreads();
  for (int e = e0 + t; e < e1; e += 256) {
    int d = ei[E_ + e];
    int b = d >> 7;
    int pos = base[b] + atomicAdd(&cnt[b], 1);
    ebuf[(size_t)b * CAP + pos] =
        (unsigned)ei[e] | ((unsigned)et[e] << 17) | ((unsigned)(d & 127) << 19);
  }
}

__global__ void k_bscan(const int* __restrict__ gbuck, int* __restrict__ bbase,
                        int* __restrict__ offsets, int nbuck, int n, int E_) {
  __shared__ int s[256];
  int t = threadIdx.x;
  int c[4]; int sum = 0;
  #pragma unroll
  for (int k = 0; k < 4; k++) {
    int i = t*4 + k;
    c[k] = (i < nbuck) ? gbuck[i] : 0;
    sum += c[k];
  }
  s[t] = sum; __syncthreads();
  for (int off = 1; off < 256; off <<= 1) {
    int v = (t >= off) ? s[t - off] : 0;
    __syncthreads();
    s[t] += v;
    __syncthreads();
  }
  int run = s[t] - sum;
  #pragma unroll
  for (int k = 0; k < 4; k++) {
    int i = t*4 + k;
    if (i < nbuck) bbase[i] = run;
    run += c[k];
  }
  if (t == 0) offsets[n] = E_;
}

__global__ __launch_bounds__(256) void k_sort(const unsigned int* __restrict__ ebuf,
    const int* __restrict__ gbuck, const int* __restrict__ bbase,
    int* __restrict__ offsets, int* __restrict__ elist, int n) {
  __shared__ int cnt[128], cur[128], sc[128];
  int b = blockIdx.x, t = threadIdx.x;
  int m = gbuck[b];
  int bb = bbase[b];
  if (t < 128) cnt[t] = 0;
  __syncthreads();
  const unsigned int* eb = ebuf + (size_t)b * CAP;
  for (int i = t; i < m; i += 256)
    atomicAdd(&cnt[(eb[i] >> 19) & 127], 1);
  __syncthreads();
  if (t < 128) sc[t] = cnt[t];
  __syncthreads();
  for (int off = 1; off < 128; off <<= 1) {
    int v = (t >= off && t < 128) ? sc[t - off] : 0;
    __syncthreads();
    if (t < 128) sc[t] += v;
    __syncthreads();
  }
  if (t < 128) {
    int excl = sc[t] - cnt[t];
    cur[t] = excl;
    int dst = b * 128 + t;
    if (dst < n) offsets[dst] = bb + excl;
  }
  __syncthreads();
  for (int i = t; i < m; i += 256) {
    unsigned int w = eb[i];
    int dl = (w >> 19) & 127;
    int p = bb + atomicAdd(&cur[dl], 1);
    elist[p] = (int)((w & 0x1FFFFu) | (((w >> 17) & 3u) << 20));
  }
}

// ---------------- K3: 16-lane-group-per-dst softmax + aggregation, bf16 output ----------------
// No max-shift: scores ~N(0,3.4), exp(s) safe in fp32; alpha identical to ref to ~1e-10.
__global__ __launch_bounds__(256) void k3_agg(
    const int* __restrict__ offsets, const int* __restrict__ elist,
    const float* __restrict__ nq, const float* __restrict__ skb,
    const unsigned short* __restrict__ vb, unsigned short* __restrict__ aggb, int n) {
  int t = threadIdx.x;
  int g = t >> 4, s = t & 15;
  int dst = blockIdx.x * 16 + g;
  __shared__ float s_esc[16][17][4];   // [17]: group bank offsets distinct -> no conflicts
  __shared__ int s_src[16][17];
  if (dst >= n) return;
  int off0 = offsets[dst];
  int deg = offsets[dst + 1] - off0;
  int h = s >> 2;                       // head of my 8 dims [s*8 .. s*8+8)
  unsigned short* orow = &aggb[(size_t)dst*HD + s*8];
  if (deg == 0) {
    *(uint4*)orow = make_uint4(0u, 0u, 0u, 0u);
    return;
  }
  float4 sk4 = *(const float4*)(&skb[(size_t)dst*4]);
  float dp0 = 0.f, dp1 = 0.f, dp2 = 0.f, dp3 = 0.f;
  float a0=0.f,a1=0.f,a2=0.f,a3=0.f,a4=0.f,a5=0.f,a6=0.f,a7=0.f;
  for (int bas = 0; bas < deg; bas += 16) {
    int cnt = min(16, deg - bas);
    float e0 = 0.f, e1 = 0.f, e2 = 0.f, e3 = 0.f;
    int src = 0;
    if (s < cnt) {
      int p = elist[off0 + bas + s];
      src = p & 0xFFFFF;
      int ety = p >> 20;
      float4 sq4 = *(const float4*)(&nq[(size_t)src*16]);
      float4 qe4 = *(const float4*)(&nq[(size_t)src*16 + 4 + ety*4]);
      float s0 = sq4.x + sk4.x; s0 = (s0 >= 0.f ? s0 : NEG*s0) + qe4.x; e0 = __expf(s0);
      float s1 = sq4.y + sk4.y; s1 = (s1 >= 0.f ? s1 : NEG*s1) + qe4.y; e1 = __expf(s1);
      float s2 = sq4.z + sk4.z; s2 = (s2 >= 0.f ? s2 : NEG*s2) + qe4.z; e2 = __expf(s2);
      float s3 = sq4.w + sk4.w; s3 = (s3 >= 0.f ? s3 : NEG*s3) + qe4.w; e3 = __expf(s3);
      dp0 += e0; dp1 += e1; dp2 += e2; dp3 += e3;
    }
    s_src[g][s] = src;
    *(float4*)(&s_esc[g][s][0]) = make_float4(e0, e1, e2, e3);
    __builtin_amdgcn_wave_barrier();
    int e = 0;
    for (; e + 2 <= cnt; e += 2) {       // 2 gathers in flight per lane
      float al0 = s_esc[g][e+0][h], al1 = s_esc[g][e+1][h];
      int se0 = s_src[g][e+0], se1 = s_src[g][e+1];
      uint4 v0 = *(const uint4*)(vb + (size_t)se0*HD + s*8);
      uint4 v1 = *(const uint4*)(vb + (size_t)se1*HD + s*8);
      a0 += al0 * __uint_as_float(v0.x << 16);
      a1 += al0 * __uint_as_float(v0.x & 0xFFFF0000u);
      a2 += al0 * __uint_as_float(v0.y << 16);
      a3 += al0 * __uint_as_float(v0.y & 0xFFFF0000u);
      a4 += al0 * __uint_as_float(v0.z << 16);
      a5 += al0 * __uint_as_float(v0.z & 0xFFFF0000u);
      a6 += al0 * __uint_as_float(v0.w << 16);
      a7 += al0 * __uint_as_float(v0.w & 0xFFFF0000u);
      a0 += al1 * __uint_as_float(v1.x << 16);
      a1 += al1 * __uint_as_float(v1.x & 0xFFFF0000u);
      a2 += al1 * __uint_as_float(v1.y << 16);
      a3 += al1 * __uint_as_float(v1.y & 0xFFFF0000u);
      a4 += al1 * __uint_as_float(v1.z << 16);
      a5 += al1 * __uint_as_float(v1.z & 0xFFFF0000u);
      a6 += al1 * __uint_as_float(v1.w << 16);
      a7 += al1 * __uint_as_float(v1.w & 0xFFFF0000u);
    }
    for (; e < cnt; e++) {
      float a = s_esc[g][e][h];
      int se = s_src[g][e];
      uint4 vv = *(const uint4*)(vb + (size_t)se*HD + s*8);
      a0 += a * __uint_as_float(vv.x << 16);
      a1 += a * __uint_as_float(vv.x & 0xFFFF0000u);
      a2 += a * __uint_as_float(vv.y << 16);
      a3 += a * __uint_as_float(vv.y & 0xFFFF0000u);
      a4 += a * __uint_as_float(vv.z << 16);
      a5 += a * __uint_as_float(vv.z & 0xFFFF0000u);
      a6 += a * __uint_as_float(vv.w << 16);
      a7 += a * __uint_as_float(vv.w & 0xFFFF0000u);
    }
    __builtin_amdgcn_wave_barrier();
  }
  #pragma unroll
  for (int off = 1; off < 16; off <<= 1) {
    dp0 += __shfl_xor(dp0, off);
    dp1 += __shfl_xor(dp1, off);
    dp2 += __shfl_xor(dp2, off);
    dp3 += __shfl_xor(dp3, off);
  }
  float den = (h == 0) ? dp0 : (h == 1) ? dp1 : (h == 2) ? dp2 : dp3;
  float inv = 1.f / (den + 1e-10f);
  uint4 pk;
  pk.x = (unsigned)f2bf(a0*inv) | ((unsigned)f2bf(a1*inv) << 16);
  pk.y = (unsigned)f2bf(a2*inv) | ((unsigned)f2bf(a3*inv) << 16);
  pk.z = (unsigned)f2bf(a4*inv) | ((unsigned)f2bf(a5*inv) << 16);
  pk.w = (unsigned)f2bf(a6*inv) | ((unsigned)f2bf(a7*inv) << 16);
  *(uint4*)orow = pk;
}

// ---------------- K4: MFMA GEMM  out = aggb @ Wout + bout ----------------
// LDS holds ONLY B (32KB, linear copy of pre-swizzled panel) -> 5 blocks/CU.
// A fragments (bf16) load global->VGPR directly, no conversion.
__global__ __launch_bounds__(256) void k4_gemm(const unsigned short* __restrict__ aggb,
    const uint4* __restrict__ Woutt, const float* __restrict__ bout,
    float* __restrict__ out, int n) {
  __shared__ uint4 ldsB[2048]; // 32KB
  int t = threadIdx.x;
  #pragma unroll
  for (int i = 0; i < 8; i++) ldsB[i*256 + t] = Woutt[i*256 + t];
  int wv = t >> 6, lane = t & 63;
  int l15 = lane & 15, l16 = lane >> 4;
  int base = blockIdx.x * 64;
  int arow = base + wv*16 + l15;
  int rr = min(arow, n - 1);
  const unsigned short* ar = &aggb[(size_t)rr*HD + l16*8];
  short8 afr[4];
  #pragma unroll
  for (int kk = 0; kk < 4; kk++)
    afr[kk] = *(const short8*)(ar + kk*32);
  __syncthreads();
  f32x4 acc[8];
  #pragma unroll
  for (int nt = 0; nt < 8; nt++) acc[nt] = (f32x4){0.f, 0.f, 0.f, 0.f};
  #pragma unroll
  for (int nt = 0; nt < 8; nt++) {
    int bcol = nt*16 + l15;
    #pragma unroll
    for (int kk = 0; kk < 4; kk++) {
      int bytec = kk*64 + l16*16;
      short8 b = *(const short8*)((const char*)ldsB + ((bcol*256 + bytec) ^ ((bcol & 7) << 4)));
      acc[nt] = __builtin_amdgcn_mfma_f32_16x16x32_bf16(afr[kk], b, acc[nt], 0, 0, 0);
    }
  }
  int rowbase = base + wv*16 + l16*4;
  #pragma unroll
  for (int nt = 0; nt < 8; nt++) {
    int col = nt*16 + l15;
    float bv = bout[col];
    #pragma unroll
    for (int r = 0; r < 4; r++) {
      int row = rowbase + r;
      if (row < n) out[(size_t)row*OUTD + col] = acc[nt][r] + bv;
    }
  }
}

extern "C" void kernel_launch(void* const* d_in, const int* in_sizes, int n_in,
                              void* d_out, int out_size, void* d_ws, size_t ws_size,
                              hipStream_t stream) {
  const float* x    = (const float*)d_in[0];
  const float* Wq   = (const float*)d_in[1];
  const float* Wk   = (const float*)d_in[2];
  const float* Wv   = (const float*)d_in[3];
  const float* attn = (const float*)d_in[4];
  const float* ee   = (const float*)d_in[5];
  const float* Wout = (const float*)d_in[6];
  const float* bout = (const float*)d_in[7];
  const int*   ei   = (const int*)d_in[8];
  const int*   et   = (const int*)d_in[9];
  int n  = in_sizes[0] / IND;
  int E_ = in_sizes[9];
  float* out = (float*)d_out;
  int nbuck = (n + 127) >> 7;

  char* w = (char*)d_ws;
  auto alloc = [&](size_t bytes) {
    char* p = w;
    w += (bytes + 255) & ~(size_t)255;
    return p;
  };
  unsigned short* vb    = (unsigned short*)alloc((size_t)n * HD * 2);
  unsigned short* aggb  = (unsigned short*)alloc((size_t)n * HD * 2);
  float* nq       = (float*)alloc((size_t)n * 16 * 4);
  float* skb      = (float*)alloc((size_t)n * 4 * 4);
  float* Wred     = (float*)alloc(128 * 20 * 4);
  unsigned short* Wallt = (unsigned short*)alloc(160 * 128 * 2);
  unsigned short* Woutt = (unsigned short*)alloc(128 * 128 * 2);
  unsigned int* ebuf = (unsigned int*)alloc((size_t)nbuck * CAP * 4);
  int*   gbuck    = (int*)alloc((size_t)nbuck * 4);
  int*   bbase    = (int*)alloc((size_t)nbuck * 4);
  int*   offsets  = (int*)alloc(((size_t)n + 1) * 4);
  int*   elist    = (int*)alloc((size_t)E_ * 4);

  hipMemsetAsync(gbuck, 0, (size_t)nbuck * 4, stream);
  k0_wred<<<1, 128, 0, stream>>>(Wq, Wk, attn, ee, Wred);
  k0b_pack<<<288, 128, 0, stream>>>(Wv, Wred, Wout, Wallt, Woutt);
  k1_gemm<<<(n + 63)/64, 256, 0, stream>>>(x, (const uint4*)Wallt, vb, nq, skb, n);
  int per = (E_ + 127) / 128;
  k_bucket<<<128, 256, 0, stream>>>(ei, et, gbuck, ebuf, E_, nbuck, per);
  k_bscan<<<1, 256, 0, stream>>>(gbuck, bbase, offsets, nbuck, n, E_);
  k_sort<<<nbuck, 256, 0, stream>>>(ebuf, gbuck, bbase, offsets, elist, n);
  k3_agg<<<(n + 15)/16, 256, 0, stream>>>(offsets, elist, nq, skb, vb, aggb, n);
  k4_gemm<<<(n + 63)/64, 256, 0, stream>>>(aggb, (const uint4*)Woutt, bout, out, n);
}

// Round 8
// 125.483 us; speedup vs baseline: 1.4727x; 1.0365x over previous
//
#include <hip/hip_runtime.h>
#include <hip/hip_bf16.h>

#define H_   4
#define D_   32
#define HD   128   // H*D
#define IND  128
#define OUTD 128
#define NET  3
#define NEG  0.2f
#define CAP  2048  // bucket capacity (expected ~819 edges/bucket, P(>2048) ~ 0)

typedef short short8 __attribute__((ext_vector_type(8)));
typedef float f32x4  __attribute__((ext_vector_type(4)));

__device__ __forceinline__ unsigned short f2bf(float f) {
  union { __hip_bfloat16 b; unsigned short u; } x;
  x.b = __float2bfloat16(f);
  return x.u;
}

__device__ __forceinline__ short8 pack_bf8(float4 lo, float4 hi) {
  union { short8 s; unsigned short u[8]; } r;
  r.u[0] = f2bf(lo.x); r.u[1] = f2bf(lo.y); r.u[2] = f2bf(lo.z); r.u[3] = f2bf(lo.w);
  r.u[4] = f2bf(hi.x); r.u[5] = f2bf(hi.y); r.u[6] = f2bf(hi.z); r.u[7] = f2bf(hi.w);
  return r.s;
}

// ---------------- K0: fold attn_lin / edge_embed into reduced weights; zero gbuck ----------------
// Wred[i][c], c in [0,20): c<4 -> sq(h=c); 4..15 -> qe(t,h); 16..19 -> sk(h)
__global__ void k0_wred(const float* __restrict__ Wq, const float* __restrict__ Wk,
                        const float* __restrict__ attn, const float* __restrict__ ee,
                        float* __restrict__ Wred, int* __restrict__ gbuck, int nbuck) {
  int i = threadIdx.x; // 0..127
  for (int k = i; k < nbuck; k += 128) gbuck[k] = 0;   // replaces hipMemsetAsync
  for (int h = 0; h < H_; h++) {
    float sq = 0.f, sk = 0.f;
    for (int d = 0; d < D_; d++) {
      sq += Wq[i*HD + h*D_ + d] * attn[h*2*D_ + d];
      sk += Wk[i*HD + h*D_ + d] * attn[h*2*D_ + D_ + d];
    }
    Wred[i*20 + h] = sq;
    Wred[i*20 + 16 + h] = sk;
    for (int t = 0; t < NET; t++) {
      float qe = 0.f;
      for (int d = 0; d < D_; d++)
        qe += Wq[i*HD + h*D_ + d] * ee[t*HD + h*D_ + d];
      Wred[i*20 + 4 + t*4 + h] = qe;
    }
  }
}

// ---------------- K0b: build PRE-SWIZZLED transposed bf16 weight panels ----------------
// Logical Wallt[c][i] stored at ushort index (c*128+i) ^ ((c&7)<<3): a LINEAR
// copy into LDS yields the XOR-swizzled layout (conflict-free ds_read_b128).
__global__ void k0b_pack(const float* __restrict__ Wv, const float* __restrict__ Wred,
                         const float* __restrict__ Wout,
                         unsigned short* __restrict__ Wallt,
                         unsigned short* __restrict__ Woutt) {
  int b = blockIdx.x, i = threadIdx.x; // i = K index
  if (b < 160) {
    int c = b;
    float val = (c < 128) ? Wv[i*HD + c] : (c < 148) ? Wred[i*20 + (c-128)] : 0.f;
    Wallt[(c*128 + i) ^ ((c & 7) << 3)] = f2bf(val);
  } else {
    int c = b - 160;
    Woutt[(c*128 + i) ^ ((c & 7) << 3)] = f2bf(Wout[i*OUTD + c]);
  }
}

// ---------------- K1: MFMA GEMM  x(n,128) @ [Wv|Wred](128,160) ----------------
// LDS holds ONLY B (40KB linear copy of pre-swizzled panel); A global->VGPR.
__global__ __launch_bounds__(256) void k1_gemm(const float* __restrict__ x,
    const uint4* __restrict__ Wallt,
    unsigned short* __restrict__ vb, float* __restrict__ nq,
    float* __restrict__ skb, int n) {
  __shared__ uint4 ldsB[2560]; // 40KB
  int t = threadIdx.x;
  #pragma unroll
  for (int i = 0; i < 10; i++) ldsB[i*256 + t] = Wallt[i*256 + t];
  int wv = t >> 6, lane = t & 63;
  int l15 = lane & 15, l16 = lane >> 4;
  int base = blockIdx.x * 64;
  int arow = base + wv*16 + l15;
  int rr = min(arow, n - 1);
  const float* xr = &x[(size_t)rr*IND + l16*8];
  short8 afr[4];
  #pragma unroll
  for (int kk = 0; kk < 4; kk++) {
    float4 lo = *(const float4*)(xr + kk*32);
    float4 hi = *(const float4*)(xr + kk*32 + 4);
    afr[kk] = pack_bf8(lo, hi);
  }
  __syncthreads();
  f32x4 acc[10];
  #pragma unroll
  for (int nt = 0; nt < 10; nt++) acc[nt] = (f32x4){0.f, 0.f, 0.f, 0.f};
  #pragma unroll
  for (int nt = 0; nt < 10; nt++) {
    int bcol = nt*16 + l15;
    #pragma unroll
    for (int kk = 0; kk < 4; kk++) {
      int bytec = kk*64 + l16*16;
      short8 b = *(const short8*)((const char*)ldsB + ((bcol*256 + bytec) ^ ((bcol & 7) << 4)));
      acc[nt] = __builtin_amdgcn_mfma_f32_16x16x32_bf16(afr[kk], b, acc[nt], 0, 0, 0);
    }
  }
  int rowbase = base + wv*16 + l16*4;
  #pragma unroll
  for (int nt = 0; nt < 10; nt++) {
    int col = nt*16 + l15;
    #pragma unroll
    for (int r = 0; r < 4; r++) {
      int row = rowbase + r;
      if (row >= n) continue;
      float val = acc[nt][r];
      if (nt < 8)       vb[(size_t)row*HD + col] = f2bf(val);
      else if (nt == 8) nq[(size_t)row*16 + (col - 128)] = val;
      else { int c = col - 144; if (c < 4) skb[(size_t)row*4 + c] = val; }
    }
  }
}

// ---------------- K2: two-level bucketed CSR build ----------------
__global__ __launch_bounds__(256) void k_bucket(const int* __restrict__ ei,
    const int* __restrict__ et, int* __restrict__ gbuck,
    unsigned int* __restrict__ ebuf, int E_, int nbuck, int per) {
  __shared__ int cnt[1024];
  __shared__ int base[1024];
  int t = threadIdx.x;
  for (int i = t; i < nbuck; i += 256) cnt[i] = 0;
  __syncthreads();
  int e0 = blockIdx.x * per;
  int e1 = min(e0 + per, E_);
  for (int e = e0 + t; e < e1; e += 256)
    atomicAdd(&cnt[ei[E_ + e] >> 7], 1);
  __syncthreads();
  for (int i = t; i < nbuck; i += 256) {
    int c = cnt[i];
    base[i] = c ? atomicAdd(&gbuck[i], c) : 0;
    cnt[i] = 0;
  }
  __syncthreads();
  for (int e = e0 + t; e < e1; e += 256) {
    int d = ei[E_ + e];
    int b = d >> 7;
    int pos = base[b] + atomicAdd(&cnt[b], 1);
    ebuf[(size_t)b * CAP + pos] =
        (unsigned)ei[e] | ((unsigned)et[e] << 17) | ((unsigned)(d & 127) << 19);
  }
}

__global__ void k_bscan(const int* __restrict__ gbuck, int* __restrict__ bbase,
                        int* __restrict__ offsets, int nbuck, int n, int E_) {
  __shared__ int s[256];
  int t = threadIdx.x;
  int c[4]; int sum = 0;
  #pragma unroll
  for (int k = 0; k < 4; k++) {
    int i = t*4 + k;
    c[k] = (i < nbuck) ? gbuck[i] : 0;
    sum += c[k];
  }
  s[t] = sum; __syncthreads();
  for (int off = 1; off < 256; off <<= 1) {
    int v = (t >= off) ? s[t - off] : 0;
    __syncthreads();
    s[t] += v;
    __syncthreads();
  }
  int run = s[t] - sum;
  #pragma unroll
  for (int k = 0; k < 4; k++) {
    int i = t*4 + k;
    if (i < nbuck) bbase[i] = run;
    run += c[k];
  }
  if (t == 0) offsets[n] = E_;
}

__global__ __launch_bounds__(256) void k_sort(const unsigned int* __restrict__ ebuf,
    const int* __restrict__ gbuck, const int* __restrict__ bbase,
    int* __restrict__ offsets, int* __restrict__ elist, int n) {
  __shared__ int cnt[128], cur[128], sc[128];
  int b = blockIdx.x, t = threadIdx.x;
  int m = gbuck[b];
  int bb = bbase[b];
  if (t < 128) cnt[t] = 0;
  __syncthreads();
  const unsigned int* eb = ebuf + (size_t)b * CAP;
  for (int i = t; i < m; i += 256)
    atomicAdd(&cnt[(eb[i] >> 19) & 127], 1);
  __syncthreads();
  if (t < 128) sc[t] = cnt[t];
  __syncthreads();
  for (int off = 1; off < 128; off <<= 1) {
    int v = (t >= off && t < 128) ? sc[t - off] : 0;
    __syncthreads();
    if (t < 128) sc[t] += v;
    __syncthreads();
  }
  if (t < 128) {
    int excl = sc[t] - cnt[t];
    cur[t] = excl;
    int dst = b * 128 + t;
    if (dst < n) offsets[dst] = bb + excl;
  }
  __syncthreads();
  for (int i = t; i < m; i += 256) {
    unsigned int w = eb[i];
    int dl = (w >> 19) & 127;
    int p = bb + atomicAdd(&cur[dl], 1);
    elist[p] = (int)((w & 0x1FFFFu) | (((w >> 17) & 3u) << 20));
  }
}

// ---------------- K3: 16-lane-group-per-dst softmax + aggregation, bf16 output ----------------
// No max-shift: scores ~N(0,3.4), exp(s) safe in fp32; alpha identical to ref to ~1e-10.
__global__ __launch_bounds__(256) void k3_agg(
    const int* __restrict__ offsets, const int* __restrict__ elist,
    const float* __restrict__ nq, const float* __restrict__ skb,
    const unsigned short* __restrict__ vb, unsigned short* __restrict__ aggb, int n) {
  int t = threadIdx.x;
  int g = t >> 4, s = t & 15;
  int dst = blockIdx.x * 16 + g;
  __shared__ float s_esc[16][17][4];   // [17]: group bank offsets distinct -> no conflicts
  __shared__ int s_src[16][17];
  if (dst >= n) return;
  int off0 = offsets[dst];
  int deg = offsets[dst + 1] - off0;
  int h = s >> 2;                       // head of my 8 dims [s*8 .. s*8+8)
  unsigned short* orow = &aggb[(size_t)dst*HD + s*8];
  if (deg == 0) {
    *(uint4*)orow = make_uint4(0u, 0u, 0u, 0u);
    return;
  }
  float4 sk4 = *(const float4*)(&skb[(size_t)dst*4]);
  float dp0 = 0.f, dp1 = 0.f, dp2 = 0.f, dp3 = 0.f;
  float a0=0.f,a1=0.f,a2=0.f,a3=0.f,a4=0.f,a5=0.f,a6=0.f,a7=0.f;
  for (int bas = 0; bas < deg; bas += 16) {
    int cnt = min(16, deg - bas);
    float e0 = 0.f, e1 = 0.f, e2 = 0.f, e3 = 0.f;
    int src = 0;
    if (s < cnt) {
      int p = elist[off0 + bas + s];
      src = p & 0xFFFFF;
      int ety = p >> 20;
      float4 sq4 = *(const float4*)(&nq[(size_t)src*16]);
      float4 qe4 = *(const float4*)(&nq[(size_t)src*16 + 4 + ety*4]);
      float s0 = sq4.x + sk4.x; s0 = (s0 >= 0.f ? s0 : NEG*s0) + qe4.x; e0 = __expf(s0);
      float s1 = sq4.y + sk4.y; s1 = (s1 >= 0.f ? s1 : NEG*s1) + qe4.y; e1 = __expf(s1);
      float s2 = sq4.z + sk4.z; s2 = (s2 >= 0.f ? s2 : NEG*s2) + qe4.z; e2 = __expf(s2);
      float s3 = sq4.w + sk4.w; s3 = (s3 >= 0.f ? s3 : NEG*s3) + qe4.w; e3 = __expf(s3);
      dp0 += e0; dp1 += e1; dp2 += e2; dp3 += e3;
    }
    s_src[g][s] = src;
    *(float4*)(&s_esc[g][s][0]) = make_float4(e0, e1, e2, e3);
    __builtin_amdgcn_wave_barrier();
    int e = 0;
    for (; e + 4 <= cnt; e += 4) {       // 4 gathers in flight per lane
      float al0 = s_esc[g][e+0][h], al1 = s_esc[g][e+1][h];
      float al2 = s_esc[g][e+2][h], al3 = s_esc[g][e+3][h];
      int se0 = s_src[g][e+0], se1 = s_src[g][e+1];
      int se2 = s_src[g][e+2], se3 = s_src[g][e+3];
      uint4 v0 = *(const uint4*)(vb + (size_t)se0*HD + s*8);
      uint4 v1 = *(const uint4*)(vb + (size_t)se1*HD + s*8);
      uint4 v2 = *(const uint4*)(vb + (size_t)se2*HD + s*8);
      uint4 v3 = *(const uint4*)(vb + (size_t)se3*HD + s*8);
      a0 += al0 * __uint_as_float(v0.x << 16);
      a1 += al0 * __uint_as_float(v0.x & 0xFFFF0000u);
      a2 += al0 * __uint_as_float(v0.y << 16);
      a3 += al0 * __uint_as_float(v0.y & 0xFFFF0000u);
      a4 += al0 * __uint_as_float(v0.z << 16);
      a5 += al0 * __uint_as_float(v0.z & 0xFFFF0000u);
      a6 += al0 * __uint_as_float(v0.w << 16);
      a7 += al0 * __uint_as_float(v0.w & 0xFFFF0000u);
      a0 += al1 * __uint_as_float(v1.x << 16);
      a1 += al1 * __uint_as_float(v1.x & 0xFFFF0000u);
      a2 += al1 * __uint_as_float(v1.y << 16);
      a3 += al1 * __uint_as_float(v1.y & 0xFFFF0000u);
      a4 += al1 * __uint_as_float(v1.z << 16);
      a5 += al1 * __uint_as_float(v1.z & 0xFFFF0000u);
      a6 += al1 * __uint_as_float(v1.w << 16);
      a7 += al1 * __uint_as_float(v1.w & 0xFFFF0000u);
      a0 += al2 * __uint_as_float(v2.x << 16);
      a1 += al2 * __uint_as_float(v2.x & 0xFFFF0000u);
      a2 += al2 * __uint_as_float(v2.y << 16);
      a3 += al2 * __uint_as_float(v2.y & 0xFFFF0000u);
      a4 += al2 * __uint_as_float(v2.z << 16);
      a5 += al2 * __uint_as_float(v2.z & 0xFFFF0000u);
      a6 += al2 * __uint_as_float(v2.w << 16);
      a7 += al2 * __uint_as_float(v2.w & 0xFFFF0000u);
      a0 += al3 * __uint_as_float(v3.x << 16);
      a1 += al3 * __uint_as_float(v3.x & 0xFFFF0000u);
      a2 += al3 * __uint_as_float(v3.y << 16);
      a3 += al3 * __uint_as_float(v3.y & 0xFFFF0000u);
      a4 += al3 * __uint_as_float(v3.z << 16);
      a5 += al3 * __uint_as_float(v3.z & 0xFFFF0000u);
      a6 += al3 * __uint_as_float(v3.w << 16);
      a7 += al3 * __uint_as_float(v3.w & 0xFFFF0000u);
    }
    for (; e < cnt; e++) {
      float a = s_esc[g][e][h];
      int se = s_src[g][e];
      uint4 vv = *(const uint4*)(vb + (size_t)se*HD + s*8);
      a0 += a * __uint_as_float(vv.x << 16);
      a1 += a * __uint_as_float(vv.x & 0xFFFF0000u);
      a2 += a * __uint_as_float(vv.y << 16);
      a3 += a * __uint_as_float(vv.y & 0xFFFF0000u);
      a4 += a * __uint_as_float(vv.z << 16);
      a5 += a * __uint_as_float(vv.z & 0xFFFF0000u);
      a6 += a * __uint_as_float(vv.w << 16);
      a7 += a * __uint_as_float(vv.w & 0xFFFF0000u);
    }
    __builtin_amdgcn_wave_barrier();
  }
  #pragma unroll
  for (int off = 1; off < 16; off <<= 1) {
    dp0 += __shfl_xor(dp0, off);
    dp1 += __shfl_xor(dp1, off);
    dp2 += __shfl_xor(dp2, off);
    dp3 += __shfl_xor(dp3, off);
  }
  float den = (h == 0) ? dp0 : (h == 1) ? dp1 : (h == 2) ? dp2 : dp3;
  float inv = 1.f / (den + 1e-10f);
  uint4 pk;
  pk.x = (unsigned)f2bf(a0*inv) | ((unsigned)f2bf(a1*inv) << 16);
  pk.y = (unsigned)f2bf(a2*inv) | ((unsigned)f2bf(a3*inv) << 16);
  pk.z = (unsigned)f2bf(a4*inv) | ((unsigned)f2bf(a5*inv) << 16);
  pk.w = (unsigned)f2bf(a6*inv) | ((unsigned)f2bf(a7*inv) << 16);
  *(uint4*)orow = pk;
}

// ---------------- K4: MFMA GEMM  out = aggb @ Wout + bout ----------------
__global__ __launch_bounds__(256) void k4_gemm(const unsigned short* __restrict__ aggb,
    const uint4* __restrict__ Woutt, const float* __restrict__ bout,
    float* __restrict__ out, int n) {
  __shared__ uint4 ldsB[2048]; // 32KB
  int t = threadIdx.x;
  #pragma unroll
  for (int i = 0; i < 8; i++) ldsB[i*256 + t] = Woutt[i*256 + t];
  int wv = t >> 6, lane = t & 63;
  int l15 = lane & 15, l16 = lane >> 4;
  int base = blockIdx.x * 64;
  int arow = base + wv*16 + l15;
  int rr = min(arow, n - 1);
  const unsigned short* ar = &aggb[(size_t)rr*HD + l16*8];
  short8 afr[4];
  #pragma unroll
  for (int kk = 0; kk < 4; kk++)
    afr[kk] = *(const short8*)(ar + kk*32);
  __syncthreads();
  f32x4 acc[8];
  #pragma unroll
  for (int nt = 0; nt < 8; nt++) acc[nt] = (f32x4){0.f, 0.f, 0.f, 0.f};
  #pragma unroll
  for (int nt = 0; nt < 8; nt++) {
    int bcol = nt*16 + l15;
    #pragma unroll
    for (int kk = 0; kk < 4; kk++) {
      int bytec = kk*64 + l16*16;
      short8 b = *(const short8*)((const char*)ldsB + ((bcol*256 + bytec) ^ ((bcol & 7) << 4)));
      acc[nt] = __builtin_amdgcn_mfma_f32_16x16x32_bf16(afr[kk], b, acc[nt], 0, 0, 0);
    }
  }
  int rowbase = base + wv*16 + l16*4;
  #pragma unroll
  for (int nt = 0; nt < 8; nt++) {
    int col = nt*16 + l15;
    float bv = bout[col];
    #pragma unroll
    for (int r = 0; r < 4; r++) {
      int row = rowbase + r;
      if (row < n) out[(size_t)row*OUTD + col] = acc[nt][r] + bv;
    }
  }
}

extern "C" void kernel_launch(void* const* d_in, const int* in_sizes, int n_in,
                              void* d_out, int out_size, void* d_ws, size_t ws_size,
                              hipStream_t stream) {
  const float* x    = (const float*)d_in[0];
  const float* Wq   = (const float*)d_in[1];
  const float* Wk   = (const float*)d_in[2];
  const float* Wv   = (const float*)d_in[3];
  const float* attn = (const float*)d_in[4];
  const float* ee   = (const float*)d_in[5];
  const float* Wout = (const float*)d_in[6];
  const float* bout = (const float*)d_in[7];
  const int*   ei   = (const int*)d_in[8];
  const int*   et   = (const int*)d_in[9];
  int n  = in_sizes[0] / IND;
  int E_ = in_sizes[9];
  float* out = (float*)d_out;
  int nbuck = (n + 127) >> 7;

  char* w = (char*)d_ws;
  auto alloc = [&](size_t bytes) {
    char* p = w;
    w += (bytes + 255) & ~(size_t)255;
    return p;
  };
  unsigned short* vb    = (unsigned short*)alloc((size_t)n * HD * 2);
  unsigned short* aggb  = (unsigned short*)alloc((size_t)n * HD * 2);
  float* nq       = (float*)alloc((size_t)n * 16 * 4);
  float* skb      = (float*)alloc((size_t)n * 4 * 4);
  float* Wred     = (float*)alloc(128 * 20 * 4);
  unsigned short* Wallt = (unsigned short*)alloc(160 * 128 * 2);
  unsigned short* Woutt = (unsigned short*)alloc(128 * 128 * 2);
  unsigned int* ebuf = (unsigned int*)alloc((size_t)nbuck * CAP * 4);
  int*   gbuck    = (int*)alloc((size_t)nbuck * 4);
  int*   bbase    = (int*)alloc((size_t)nbuck * 4);
  int*   offsets  = (int*)alloc(((size_t)n + 1) * 4);
  int*   elist    = (int*)alloc((size_t)E_ * 4);

  k0_wred<<<1, 128, 0, stream>>>(Wq, Wk, attn, ee, Wred, gbuck, nbuck);
  k0b_pack<<<288, 128, 0, stream>>>(Wv, Wred, Wout, Wallt, Woutt);
  k1_gemm<<<(n + 63)/64, 256, 0, stream>>>(x, (const uint4*)Wallt, vb, nq, skb, n);
  int per = (E_ + 127) / 128;
  k_bucket<<<128, 256, 0, stream>>>(ei, et, gbuck, ebuf, E_, nbuck, per);
  k_bscan<<<1, 256, 0, stream>>>(gbuck, bbase, offsets, nbuck, n, E_);
  k_sort<<<nbuck, 256, 0, stream>>>(ebuf, gbuck, bbase, offsets, elist, n);
  k3_agg<<<(n + 15)/16, 256, 0, stream>>>(offsets, elist, nq, skb, vb, aggb, n);
  k4_gemm<<<(n + 63)/64, 256, 0, stream>>>(aggb, (const uint4*)Woutt, bout, out, n);
}

// Round 9
// 117.174 us; speedup vs baseline: 1.5772x; 1.0709x over previous
//
#include <hip/hip_runtime.h>
#include <hip/hip_bf16.h>

#define H_   4
#define D_   32
#define HD   128   // H*D
#define IND  128
#define OUTD 128
#define NET  3
#define NEG  0.2f
#define CAP  2048  // bucket capacity (expected ~819 edges/bucket, P(>2048) ~ 0)

typedef short short8 __attribute__((ext_vector_type(8)));
typedef float f32x4  __attribute__((ext_vector_type(4)));

__device__ __forceinline__ unsigned short f2bf(float f) {
  union { __hip_bfloat16 b; unsigned short u; } x;
  x.b = __float2bfloat16(f);
  return x.u;
}

__device__ __forceinline__ short8 pack_bf8(float4 lo, float4 hi) {
  union { short8 s; unsigned short u[8]; } r;
  r.u[0] = f2bf(lo.x); r.u[1] = f2bf(lo.y); r.u[2] = f2bf(lo.z); r.u[3] = f2bf(lo.w);
  r.u[4] = f2bf(hi.x); r.u[5] = f2bf(hi.y); r.u[6] = f2bf(hi.z); r.u[7] = f2bf(hi.w);
  return r.s;
}

// ---------------- K0b: pre-swizzled bf16 weight panels + inline Wred + gbuck zero ----------------
// Logical Wallt[c][i] stored at ushort index (c*128+i) ^ ((c&7)<<3): a LINEAR
// copy into LDS yields the XOR-swizzled layout (conflict-free ds_read_b128).
// Wallt cols 128..147 are the reduced weights (sq/qe/sk), computed inline here.
__global__ void k0b_pack(const float* __restrict__ Wq, const float* __restrict__ Wk,
                         const float* __restrict__ attn, const float* __restrict__ ee,
                         const float* __restrict__ Wv, const float* __restrict__ Wout,
                         unsigned short* __restrict__ Wallt,
                         unsigned short* __restrict__ Woutt,
                         int* __restrict__ gbuck, int nbuck) {
  int b = blockIdx.x, i = threadIdx.x; // i = K index
  if (b == 288) {
    for (int k = i; k < nbuck; k += 128) gbuck[k] = 0;  // replaces hipMemsetAsync
    return;
  }
  if (b < 160) {
    int c = b;
    float val = 0.f;
    if (c < 128) {
      val = Wv[i*HD + c];
    } else {
      int cc = c - 128;
      if (cc < 4) {                      // sq(h)
        int h = cc;
        for (int d = 0; d < D_; d++) val += Wq[i*HD + h*D_ + d] * attn[h*2*D_ + d];
      } else if (cc < 16) {              // qe(t,h)
        int t2 = (cc - 4) >> 2, h = (cc - 4) & 3;
        for (int d = 0; d < D_; d++) val += Wq[i*HD + h*D_ + d] * ee[t2*HD + h*D_ + d];
      } else if (cc < 20) {              // sk(h)
        int h = cc - 16;
        for (int d = 0; d < D_; d++) val += Wk[i*HD + h*D_ + d] * attn[h*2*D_ + D_ + d];
      }
    }
    Wallt[(c*128 + i) ^ ((c & 7) << 3)] = f2bf(val);
  } else {
    int c = b - 160;
    Woutt[(c*128 + i) ^ ((c & 7) << 3)] = f2bf(Wout[i*OUTD + c]);
  }
}

// ---------------- K1: MFMA GEMM  x(n,128) @ [Wv|Wred](128,160) ----------------
// LDS holds ONLY B (40KB linear copy of pre-swizzled panel); A global->VGPR.
__global__ __launch_bounds__(256) void k1_gemm(const float* __restrict__ x,
    const uint4* __restrict__ Wallt,
    unsigned short* __restrict__ vb, float* __restrict__ nq,
    float* __restrict__ skb, int n) {
  __shared__ uint4 ldsB[2560]; // 40KB
  int t = threadIdx.x;
  #pragma unroll
  for (int i = 0; i < 10; i++) ldsB[i*256 + t] = Wallt[i*256 + t];
  int wv = t >> 6, lane = t & 63;
  int l15 = lane & 15, l16 = lane >> 4;
  int base = blockIdx.x * 64;
  int arow = base + wv*16 + l15;
  int rr = min(arow, n - 1);
  const float* xr = &x[(size_t)rr*IND + l16*8];
  short8 afr[4];
  #pragma unroll
  for (int kk = 0; kk < 4; kk++) {
    float4 lo = *(const float4*)(xr + kk*32);
    float4 hi = *(const float4*)(xr + kk*32 + 4);
    afr[kk] = pack_bf8(lo, hi);
  }
  __syncthreads();
  f32x4 acc[10];
  #pragma unroll
  for (int nt = 0; nt < 10; nt++) acc[nt] = (f32x4){0.f, 0.f, 0.f, 0.f};
  #pragma unroll
  for (int nt = 0; nt < 10; nt++) {
    int bcol = nt*16 + l15;
    #pragma unroll
    for (int kk = 0; kk < 4; kk++) {
      int bytec = kk*64 + l16*16;
      short8 b = *(const short8*)((const char*)ldsB + ((bcol*256 + bytec) ^ ((bcol & 7) << 4)));
      acc[nt] = __builtin_amdgcn_mfma_f32_16x16x32_bf16(afr[kk], b, acc[nt], 0, 0, 0);
    }
  }
  int rowbase = base + wv*16 + l16*4;
  #pragma unroll
  for (int nt = 0; nt < 10; nt++) {
    int col = nt*16 + l15;
    #pragma unroll
    for (int r = 0; r < 4; r++) {
      int row = rowbase + r;
      if (row >= n) continue;
      float val = acc[nt][r];
      if (nt < 8)       vb[(size_t)row*HD + col] = f2bf(val);
      else if (nt == 8) nq[(size_t)row*16 + (col - 128)] = val;
      else { int c = col - 144; if (c < 4) skb[(size_t)row*4 + c] = val; }
    }
  }
}

// ---------------- K2: two-level bucketed CSR build ----------------
__global__ __launch_bounds__(256) void k_bucket(const int* __restrict__ ei,
    const int* __restrict__ et, int* __restrict__ gbuck,
    unsigned int* __restrict__ ebuf, int E_, int nbuck, int per) {
  __shared__ int cnt[1024];
  __shared__ int base[1024];
  int t = threadIdx.x;
  for (int i = t; i < nbuck; i += 256) cnt[i] = 0;
  __syncthreads();
  int e0 = blockIdx.x * per;
  int e1 = min(e0 + per, E_);
  for (int e = e0 + t; e < e1; e += 256)
    atomicAdd(&cnt[ei[E_ + e] >> 7], 1);
  __syncthreads();
  for (int i = t; i < nbuck; i += 256) {
    int c = cnt[i];
    base[i] = c ? atomicAdd(&gbuck[i], c) : 0;
    cnt[i] = 0;
  }
  __syncthreads();
  for (int e = e0 + t; e < e1; e += 256) {
    int d = ei[E_ + e];
    int b = d >> 7;
    int pos = base[b] + atomicAdd(&cnt[b], 1);
    ebuf[(size_t)b * CAP + pos] =
        (unsigned)ei[e] | ((unsigned)et[e] << 17) | ((unsigned)(d & 127) << 19);
  }
}

// per-bucket counting sort; computes its own bucket base from gbuck (bscan folded in)
__global__ __launch_bounds__(256) void k_sort(const unsigned int* __restrict__ ebuf,
    const int* __restrict__ gbuck, int* __restrict__ offsets,
    int* __restrict__ elist, int n, int E_) {
  __shared__ int cnt[128], cur[128], sc[128], red[256];
  int b = blockIdx.x, t = threadIdx.x;
  // bb = sum gbuck[0..b-1]
  int part = 0;
  for (int i = t; i < b; i += 256) part += gbuck[i];
  red[t] = part; __syncthreads();
  for (int off = 128; off > 0; off >>= 1) {
    if (t < off) red[t] += red[t + off];
    __syncthreads();
  }
  int bb = red[0];
  int m = gbuck[b];
  if (b == 0 && t == 0) offsets[n] = E_;
  if (t < 128) cnt[t] = 0;
  __syncthreads();
  const unsigned int* eb = ebuf + (size_t)b * CAP;
  for (int i = t; i < m; i += 256)
    atomicAdd(&cnt[(eb[i] >> 19) & 127], 1);
  __syncthreads();
  if (t < 128) sc[t] = cnt[t];
  __syncthreads();
  for (int off = 1; off < 128; off <<= 1) {
    int v = (t >= off && t < 128) ? sc[t - off] : 0;
    __syncthreads();
    if (t < 128) sc[t] += v;
    __syncthreads();
  }
  if (t < 128) {
    int excl = sc[t] - cnt[t];
    cur[t] = excl;
    int dst = b * 128 + t;
    if (dst < n) offsets[dst] = bb + excl;
  }
  __syncthreads();
  for (int i = t; i < m; i += 256) {
    unsigned int w = eb[i];
    int dl = (w >> 19) & 127;
    int p = bb + atomicAdd(&cur[dl], 1);
    elist[p] = (int)((w & 0x1FFFFu) | (((w >> 17) & 3u) << 20));
  }
}

// ---------------- K3: 8-lane-group-per-dst softmax + aggregation, bf16 output ----------------
// 32 dsts/block; lane owns 16 dims (2x16B gathers/edge -> 8 loads in flight @unroll4).
// No max-shift: scores ~N(0,3.4), exp(s) safe in fp32; alpha identical to ref to ~1e-10.
#define BF2F(x)    __uint_as_float((x) << 16)
#define BF2F_HI(x) __uint_as_float((x) & 0xFFFF0000u)
#define ACCLO(al,v) \
  a0 += al*BF2F(v.x); a1 += al*BF2F_HI(v.x); a2 += al*BF2F(v.y); a3 += al*BF2F_HI(v.y); \
  a4 += al*BF2F(v.z); a5 += al*BF2F_HI(v.z); a6 += al*BF2F(v.w); a7 += al*BF2F_HI(v.w);
#define ACCHI(al,v) \
  a8  += al*BF2F(v.x); a9  += al*BF2F_HI(v.x); a10 += al*BF2F(v.y); a11 += al*BF2F_HI(v.y); \
  a12 += al*BF2F(v.z); a13 += al*BF2F_HI(v.z); a14 += al*BF2F(v.w); a15 += al*BF2F_HI(v.w);
__global__ __launch_bounds__(256) void k3_agg(
    const int* __restrict__ offsets, const int* __restrict__ elist,
    const float* __restrict__ nq, const float* __restrict__ skb,
    const unsigned short* __restrict__ vb, unsigned short* __restrict__ aggb, int n) {
  int t = threadIdx.x;
  int g = t >> 3, s = t & 7;           // 32 groups of 8 lanes
  int dst = blockIdx.x * 32 + g;
  __shared__ float s_esc[32][10][4];   // stride 40 floats: 2-way on write (free)
  __shared__ int s_src[32][10];
  if (dst >= n) return;
  int off0 = offsets[dst];
  int deg = offsets[dst + 1] - off0;
  int h = s >> 1;                      // head of my 16 dims [s*16 .. s*16+16)
  unsigned short* orow = &aggb[(size_t)dst*HD + s*16];
  if (deg == 0) {
    *(uint4*)orow       = make_uint4(0u, 0u, 0u, 0u);
    *(uint4*)(orow + 8) = make_uint4(0u, 0u, 0u, 0u);
    return;
  }
  float4 sk4 = *(const float4*)(&skb[(size_t)dst*4]);
  float dp0 = 0.f, dp1 = 0.f, dp2 = 0.f, dp3 = 0.f;
  float a0=0.f,a1=0.f,a2=0.f,a3=0.f,a4=0.f,a5=0.f,a6=0.f,a7=0.f;
  float a8=0.f,a9=0.f,a10=0.f,a11=0.f,a12=0.f,a13=0.f,a14=0.f,a15=0.f;
  for (int bas = 0; bas < deg; bas += 8) {
    int cnt = min(8, deg - bas);
    float e0 = 0.f, e1 = 0.f, e2 = 0.f, e3 = 0.f;
    int src = 0;
    if (s < cnt) {
      int p = elist[off0 + bas + s];
      src = p & 0xFFFFF;
      int ety = p >> 20;
      float4 sq4 = *(const float4*)(&nq[(size_t)src*16]);
      float4 qe4 = *(const float4*)(&nq[(size_t)src*16 + 4 + ety*4]);
      float s0 = sq4.x + sk4.x; s0 = (s0 >= 0.f ? s0 : NEG*s0) + qe4.x; e0 = __expf(s0);
      float s1 = sq4.y + sk4.y; s1 = (s1 >= 0.f ? s1 : NEG*s1) + qe4.y; e1 = __expf(s1);
      float s2 = sq4.z + sk4.z; s2 = (s2 >= 0.f ? s2 : NEG*s2) + qe4.z; e2 = __expf(s2);
      float s3 = sq4.w + sk4.w; s3 = (s3 >= 0.f ? s3 : NEG*s3) + qe4.w; e3 = __expf(s3);
      dp0 += e0; dp1 += e1; dp2 += e2; dp3 += e3;
    }
    s_src[g][s] = src;
    *(float4*)(&s_esc[g][s][0]) = make_float4(e0, e1, e2, e3);
    __builtin_amdgcn_wave_barrier();
    int e = 0;
    for (; e + 4 <= cnt; e += 4) {     // 8 gathers in flight per lane
      float al0 = s_esc[g][e+0][h], al1 = s_esc[g][e+1][h];
      float al2 = s_esc[g][e+2][h], al3 = s_esc[g][e+3][h];
      const unsigned short* p0 = vb + (size_t)s_src[g][e+0]*HD + s*16;
      const unsigned short* p1 = vb + (size_t)s_src[g][e+1]*HD + s*16;
      const unsigned short* p2 = vb + (size_t)s_src[g][e+2]*HD + s*16;
      const unsigned short* p3 = vb + (size_t)s_src[g][e+3]*HD + s*16;
      uint4 u0 = *(const uint4*)p0, w0 = *(const uint4*)(p0 + 8);
      uint4 u1 = *(const uint4*)p1, w1 = *(const uint4*)(p1 + 8);
      uint4 u2 = *(const uint4*)p2, w2 = *(const uint4*)(p2 + 8);
      uint4 u3 = *(const uint4*)p3, w3 = *(const uint4*)(p3 + 8);
      ACCLO(al0, u0); ACCHI(al0, w0);
      ACCLO(al1, u1); ACCHI(al1, w1);
      ACCLO(al2, u2); ACCHI(al2, w2);
      ACCLO(al3, u3); ACCHI(al3, w3);
    }
    for (; e < cnt; e++) {
      float al = s_esc[g][e][h];
      const unsigned short* p = vb + (size_t)s_src[g][e]*HD + s*16;
      uint4 u = *(const uint4*)p, w = *(const uint4*)(p + 8);
      ACCLO(al, u); ACCHI(al, w);
    }
    __builtin_amdgcn_wave_barrier();
  }
  #pragma unroll
  for (int off = 1; off < 8; off <<= 1) {
    dp0 += __shfl_xor(dp0, off);
    dp1 += __shfl_xor(dp1, off);
    dp2 += __shfl_xor(dp2, off);
    dp3 += __shfl_xor(dp3, off);
  }
  float den = (h == 0) ? dp0 : (h == 1) ? dp1 : (h == 2) ? dp2 : dp3;
  float inv = 1.f / (den + 1e-10f);
  uint4 q1, q2;
  q1.x = (unsigned)f2bf(a0*inv)  | ((unsigned)f2bf(a1*inv)  << 16);
  q1.y = (unsigned)f2bf(a2*inv)  | ((unsigned)f2bf(a3*inv)  << 16);
  q1.z = (unsigned)f2bf(a4*inv)  | ((unsigned)f2bf(a5*inv)  << 16);
  q1.w = (unsigned)f2bf(a6*inv)  | ((unsigned)f2bf(a7*inv)  << 16);
  q2.x = (unsigned)f2bf(a8*inv)  | ((unsigned)f2bf(a9*inv)  << 16);
  q2.y = (unsigned)f2bf(a10*inv) | ((unsigned)f2bf(a11*inv) << 16);
  q2.z = (unsigned)f2bf(a12*inv) | ((unsigned)f2bf(a13*inv) << 16);
  q2.w = (unsigned)f2bf(a14*inv) | ((unsigned)f2bf(a15*inv) << 16);
  *(uint4*)orow       = q1;
  *(uint4*)(orow + 8) = q2;
}

// ---------------- K4: MFMA GEMM  out = aggb @ Wout + bout ----------------
__global__ __launch_bounds__(256) void k4_gemm(const unsigned short* __restrict__ aggb,
    const uint4* __restrict__ Woutt, const float* __restrict__ bout,
    float* __restrict__ out, int n) {
  __shared__ uint4 ldsB[2048]; // 32KB
  int t = threadIdx.x;
  #pragma unroll
  for (int i = 0; i < 8; i++) ldsB[i*256 + t] = Woutt[i*256 + t];
  int wv = t >> 6, lane = t & 63;
  int l15 = lane & 15, l16 = lane >> 4;
  int base = blockIdx.x * 64;
  int arow = base + wv*16 + l15;
  int rr = min(arow, n - 1);
  const unsigned short* ar = &aggb[(size_t)rr*HD + l16*8];
  short8 afr[4];
  #pragma unroll
  for (int kk = 0; kk < 4; kk++)
    afr[kk] = *(const short8*)(ar + kk*32);
  __syncthreads();
  f32x4 acc[8];
  #pragma unroll
  for (int nt = 0; nt < 8; nt++) acc[nt] = (f32x4){0.f, 0.f, 0.f, 0.f};
  #pragma unroll
  for (int nt = 0; nt < 8; nt++) {
    int bcol = nt*16 + l15;
    #pragma unroll
    for (int kk = 0; kk < 4; kk++) {
      int bytec = kk*64 + l16*16;
      short8 b = *(const short8*)((const char*)ldsB + ((bcol*256 + bytec) ^ ((bcol & 7) << 4)));
      acc[nt] = __builtin_amdgcn_mfma_f32_16x16x32_bf16(afr[kk], b, acc[nt], 0, 0, 0);
    }
  }
  int rowbase = base + wv*16 + l16*4;
  #pragma unroll
  for (int nt = 0; nt < 8; nt++) {
    int col = nt*16 + l15;
    float bv = bout[col];
    #pragma unroll
    for (int r = 0; r < 4; r++) {
      int row = rowbase + r;
      if (row < n) out[(size_t)row*OUTD + col] = acc[nt][r] + bv;
    }
  }
}

extern "C" void kernel_launch(void* const* d_in, const int* in_sizes, int n_in,
                              void* d_out, int out_size, void* d_ws, size_t ws_size,
                              hipStream_t stream) {
  const float* x    = (const float*)d_in[0];
  const float* Wq   = (const float*)d_in[1];
  const float* Wk   = (const float*)d_in[2];
  const float* Wv   = (const float*)d_in[3];
  const float* attn = (const float*)d_in[4];
  const float* ee   = (const float*)d_in[5];
  const float* Wout = (const float*)d_in[6];
  const float* bout = (const float*)d_in[7];
  const int*   ei   = (const int*)d_in[8];
  const int*   et   = (const int*)d_in[9];
  int n  = in_sizes[0] / IND;
  int E_ = in_sizes[9];
  float* out = (float*)d_out;
  int nbuck = (n + 127) >> 7;

  char* w = (char*)d_ws;
  auto alloc = [&](size_t bytes) {
    char* p = w;
    w += (bytes + 255) & ~(size_t)255;
    return p;
  };
  unsigned short* vb    = (unsigned short*)alloc((size_t)n * HD * 2);
  unsigned short* aggb  = (unsigned short*)alloc((size_t)n * HD * 2);
  float* nq       = (float*)alloc((size_t)n * 16 * 4);
  float* skb      = (float*)alloc((size_t)n * 4 * 4);
  unsigned short* Wallt = (unsigned short*)alloc(160 * 128 * 2);
  unsigned short* Woutt = (unsigned short*)alloc(128 * 128 * 2);
  unsigned int* ebuf = (unsigned int*)alloc((size_t)nbuck * CAP * 4);
  int*   gbuck    = (int*)alloc((size_t)nbuck * 4);
  int*   offsets  = (int*)alloc(((size_t)n + 1) * 4);
  int*   elist    = (int*)alloc((size_t)E_ * 4);

  k0b_pack<<<289, 128, 0, stream>>>(Wq, Wk, attn, ee, Wv, Wout, Wallt, Woutt,
                                    gbuck, nbuck);
  k1_gemm<<<(n + 63)/64, 256, 0, stream>>>(x, (const uint4*)Wallt, vb, nq, skb, n);
  int per = (E_ + 127) / 128;
  k_bucket<<<128, 256, 0, stream>>>(ei, et, gbuck, ebuf, E_, nbuck, per);
  k_sort<<<nbuck, 256, 0, stream>>>(ebuf, gbuck, offsets, elist, n, E_);
  k3_agg<<<(n + 31)/32, 256, 0, stream>>>(offsets, elist, nq, skb, vb, aggb, n);
  k4_gemm<<<(n + 63)/64, 256, 0, stream>>>(aggb, (const uint4*)Woutt, bout, out, n);
}

// Round 10
// 106.976 us; speedup vs baseline: 1.7275x; 1.0953x over previous
//
#include <hip/hip_runtime.h>
#include <hip/hip_bf16.h>

#define H_   4
#define D_   32
#define HD   128   // H*D
#define IND  128
#define OUTD 128
#define NET  3
#define NEG  0.2f
#define CAP  2048  // bucket capacity (expected ~819 edges/bucket, P(>2048) ~ 0)

typedef short short8 __attribute__((ext_vector_type(8)));
typedef float f32x4  __attribute__((ext_vector_type(4)));

__device__ __forceinline__ unsigned short f2bf(float f) {
  union { __hip_bfloat16 b; unsigned short u; } x;
  x.b = __float2bfloat16(f);
  return x.u;
}

__device__ __forceinline__ short8 pack_bf8(float4 lo, float4 hi) {
  union { short8 s; unsigned short u[8]; } r;
  r.u[0] = f2bf(lo.x); r.u[1] = f2bf(lo.y); r.u[2] = f2bf(lo.z); r.u[3] = f2bf(lo.w);
  r.u[4] = f2bf(hi.x); r.u[5] = f2bf(hi.y); r.u[6] = f2bf(hi.z); r.u[7] = f2bf(hi.w);
  return r.s;
}

// ---------------- K0b: pre-swizzled bf16 weight panels + inline Wred + gbuck zero ----------------
// Logical Wallt[c][i] stored at ushort index (c*128+i) ^ ((c&7)<<3): a LINEAR
// copy into LDS yields the XOR-swizzled layout (conflict-free ds_read_b128).
// Wallt cols 128..147 are the reduced weights (sq/qe/sk), computed inline here.
__global__ void k0b_pack(const float* __restrict__ Wq, const float* __restrict__ Wk,
                         const float* __restrict__ attn, const float* __restrict__ ee,
                         const float* __restrict__ Wv, const float* __restrict__ Wout,
                         unsigned short* __restrict__ Wallt,
                         unsigned short* __restrict__ Woutt,
                         int* __restrict__ gbuck, int nbuck) {
  int b = blockIdx.x, i = threadIdx.x; // i = K index
  if (b == 288) {
    for (int k = i; k < nbuck; k += 128) gbuck[k] = 0;  // replaces hipMemsetAsync
    return;
  }
  if (b < 160) {
    int c = b;
    float val = 0.f;
    if (c < 128) {
      val = Wv[i*HD + c];
    } else {
      int cc = c - 128;
      if (cc < 4) {                      // sq(h)
        int h = cc;
        for (int d = 0; d < D_; d++) val += Wq[i*HD + h*D_ + d] * attn[h*2*D_ + d];
      } else if (cc < 16) {              // qe(t,h)
        int t2 = (cc - 4) >> 2, h = (cc - 4) & 3;
        for (int d = 0; d < D_; d++) val += Wq[i*HD + h*D_ + d] * ee[t2*HD + h*D_ + d];
      } else if (cc < 20) {              // sk(h)
        int h = cc - 16;
        for (int d = 0; d < D_; d++) val += Wk[i*HD + h*D_ + d] * attn[h*2*D_ + D_ + d];
      }
    }
    Wallt[(c*128 + i) ^ ((c & 7) << 3)] = f2bf(val);
  } else {
    int c = b - 160;
    Woutt[(c*128 + i) ^ ((c & 7) << 3)] = f2bf(Wout[i*OUTD + c]);
  }
}

// ---------------- K1: MFMA GEMM  x(n,128) @ [Wv|Wred](128,160) ----------------
// LDS holds ONLY B (40KB linear copy of pre-swizzled panel); A global->VGPR.
__global__ __launch_bounds__(256) void k1_gemm(const float* __restrict__ x,
    const uint4* __restrict__ Wallt,
    unsigned short* __restrict__ vb, float* __restrict__ nq,
    float* __restrict__ skb, int n) {
  __shared__ uint4 ldsB[2560]; // 40KB
  int t = threadIdx.x;
  #pragma unroll
  for (int i = 0; i < 10; i++) ldsB[i*256 + t] = Wallt[i*256 + t];
  int wv = t >> 6, lane = t & 63;
  int l15 = lane & 15, l16 = lane >> 4;
  int base = blockIdx.x * 64;
  int arow = base + wv*16 + l15;
  int rr = min(arow, n - 1);
  const float* xr = &x[(size_t)rr*IND + l16*8];
  short8 afr[4];
  #pragma unroll
  for (int kk = 0; kk < 4; kk++) {
    float4 lo = *(const float4*)(xr + kk*32);
    float4 hi = *(const float4*)(xr + kk*32 + 4);
    afr[kk] = pack_bf8(lo, hi);
  }
  __syncthreads();
  f32x4 acc[10];
  #pragma unroll
  for (int nt = 0; nt < 10; nt++) acc[nt] = (f32x4){0.f, 0.f, 0.f, 0.f};
  #pragma unroll
  for (int nt = 0; nt < 10; nt++) {
    int bcol = nt*16 + l15;
    #pragma unroll
    for (int kk = 0; kk < 4; kk++) {
      int bytec = kk*64 + l16*16;
      short8 b = *(const short8*)((const char*)ldsB + ((bcol*256 + bytec) ^ ((bcol & 7) << 4)));
      acc[nt] = __builtin_amdgcn_mfma_f32_16x16x32_bf16(afr[kk], b, acc[nt], 0, 0, 0);
    }
  }
  int rowbase = base + wv*16 + l16*4;
  #pragma unroll
  for (int nt = 0; nt < 10; nt++) {
    int col = nt*16 + l15;
    #pragma unroll
    for (int r = 0; r < 4; r++) {
      int row = rowbase + r;
      if (row >= n) continue;
      float val = acc[nt][r];
      if (nt < 8)       vb[(size_t)row*HD + col] = f2bf(val);
      else if (nt == 8) nq[(size_t)row*16 + (col - 128)] = val;
      else { int c = col - 144; if (c < 4) skb[(size_t)row*4 + c] = val; }
    }
  }
}

// ---------------- K2: two-level bucketed CSR build ----------------
__global__ __launch_bounds__(256) void k_bucket(const int* __restrict__ ei,
    const int* __restrict__ et, int* __restrict__ gbuck,
    unsigned int* __restrict__ ebuf, int E_, int nbuck, int per) {
  __shared__ int cnt[1024];
  __shared__ int base[1024];
  int t = threadIdx.x;
  for (int i = t; i < nbuck; i += 256) cnt[i] = 0;
  __syncthreads();
  int e0 = blockIdx.x * per;
  int e1 = min(e0 + per, E_);
  for (int e = e0 + t; e < e1; e += 256)
    atomicAdd(&cnt[ei[E_ + e] >> 7], 1);
  __syncthreads();
  for (int i = t; i < nbuck; i += 256) {
    int c = cnt[i];
    base[i] = c ? atomicAdd(&gbuck[i], c) : 0;
    cnt[i] = 0;
  }
  __syncthreads();
  for (int e = e0 + t; e < e1; e += 256) {
    int d = ei[E_ + e];
    int b = d >> 7;
    int pos = base[b] + atomicAdd(&cnt[b], 1);
    ebuf[(size_t)b * CAP + pos] =
        (unsigned)ei[e] | ((unsigned)et[e] << 17) | ((unsigned)(d & 127) << 19);
  }
}

// per-bucket counting sort; computes its own bucket base from gbuck (bscan folded in)
__global__ __launch_bounds__(256) void k_sort(const unsigned int* __restrict__ ebuf,
    const int* __restrict__ gbuck, int* __restrict__ offsets,
    int* __restrict__ elist, int n, int E_) {
  __shared__ int cnt[128], cur[128], sc[128], red[256];
  int b = blockIdx.x, t = threadIdx.x;
  // bb = sum gbuck[0..b-1]
  int part = 0;
  for (int i = t; i < b; i += 256) part += gbuck[i];
  red[t] = part; __syncthreads();
  for (int off = 128; off > 0; off >>= 1) {
    if (t < off) red[t] += red[t + off];
    __syncthreads();
  }
  int bb = red[0];
  int m = gbuck[b];
  if (b == 0 && t == 0) offsets[n] = E_;
  if (t < 128) cnt[t] = 0;
  __syncthreads();
  const unsigned int* eb = ebuf + (size_t)b * CAP;
  for (int i = t; i < m; i += 256)
    atomicAdd(&cnt[(eb[i] >> 19) & 127], 1);
  __syncthreads();
  if (t < 128) sc[t] = cnt[t];
  __syncthreads();
  for (int off = 1; off < 128; off <<= 1) {
    int v = (t >= off && t < 128) ? sc[t - off] : 0;
    __syncthreads();
    if (t < 128) sc[t] += v;
    __syncthreads();
  }
  if (t < 128) {
    int excl = sc[t] - cnt[t];
    cur[t] = excl;
    int dst = b * 128 + t;
    if (dst < n) offsets[dst] = bb + excl;
  }
  __syncthreads();
  for (int i = t; i < m; i += 256) {
    unsigned int w = eb[i];
    int dl = (w >> 19) & 127;
    int p = bb + atomicAdd(&cur[dl], 1);
    elist[p] = (int)((w & 0x1FFFFu) | (((w >> 17) & 3u) << 20));
  }
}

// ---------------- K3: 16-lane-group-per-dst softmax + aggregation, bf16 output ----------------
// No max-shift: scores ~N(0,3.4), exp(s) safe in fp32; alpha identical to ref to ~1e-10.
__global__ __launch_bounds__(256) void k3_agg(
    const int* __restrict__ offsets, const int* __restrict__ elist,
    const float* __restrict__ nq, const float* __restrict__ skb,
    const unsigned short* __restrict__ vb, unsigned short* __restrict__ aggb, int n) {
  int t = threadIdx.x;
  int g = t >> 4, s = t & 15;
  int dst = blockIdx.x * 16 + g;
  __shared__ float s_esc[16][17][4];   // [17]: group bank offsets distinct -> no conflicts
  __shared__ int s_src[16][17];
  if (dst >= n) return;
  int off0 = offsets[dst];
  int deg = offsets[dst + 1] - off0;
  int h = s >> 2;                       // head of my 8 dims [s*8 .. s*8+8)
  unsigned short* orow = &aggb[(size_t)dst*HD + s*8];
  if (deg == 0) {
    *(uint4*)orow = make_uint4(0u, 0u, 0u, 0u);
    return;
  }
  float4 sk4 = *(const float4*)(&skb[(size_t)dst*4]);
  float dp0 = 0.f, dp1 = 0.f, dp2 = 0.f, dp3 = 0.f;
  float a0=0.f,a1=0.f,a2=0.f,a3=0.f,a4=0.f,a5=0.f,a6=0.f,a7=0.f;
  for (int bas = 0; bas < deg; bas += 16) {
    int cnt = min(16, deg - bas);
    float e0 = 0.f, e1 = 0.f, e2 = 0.f, e3 = 0.f;
    int src = 0;
    if (s < cnt) {
      int p = elist[off0 + bas + s];
      src = p & 0xFFFFF;
      int ety = p >> 20;
      float4 sq4 = *(const float4*)(&nq[(size_t)src*16]);
      float4 qe4 = *(const float4*)(&nq[(size_t)src*16 + 4 + ety*4]);
      float s0 = sq4.x + sk4.x; s0 = (s0 >= 0.f ? s0 : NEG*s0) + qe4.x; e0 = __expf(s0);
      float s1 = sq4.y + sk4.y; s1 = (s1 >= 0.f ? s1 : NEG*s1) + qe4.y; e1 = __expf(s1);
      float s2 = sq4.z + sk4.z; s2 = (s2 >= 0.f ? s2 : NEG*s2) + qe4.z; e2 = __expf(s2);
      float s3 = sq4.w + sk4.w; s3 = (s3 >= 0.f ? s3 : NEG*s3) + qe4.w; e3 = __expf(s3);
      dp0 += e0; dp1 += e1; dp2 += e2; dp3 += e3;
    }
    s_src[g][s] = src;
    *(float4*)(&s_esc[g][s][0]) = make_float4(e0, e1, e2, e3);
    __builtin_amdgcn_wave_barrier();
    int e = 0;
    for (; e + 4 <= cnt; e += 4) {       // 4 gathers in flight per lane
      float al0 = s_esc[g][e+0][h], al1 = s_esc[g][e+1][h];
      float al2 = s_esc[g][e+2][h], al3 = s_esc[g][e+3][h];
      int se0 = s_src[g][e+0], se1 = s_src[g][e+1];
      int se2 = s_src[g][e+2], se3 = s_src[g][e+3];
      uint4 v0 = *(const uint4*)(vb + (size_t)se0*HD + s*8);
      uint4 v1 = *(const uint4*)(vb + (size_t)se1*HD + s*8);
      uint4 v2 = *(const uint4*)(vb + (size_t)se2*HD + s*8);
      uint4 v3 = *(const uint4*)(vb + (size_t)se3*HD + s*8);
      a0 += al0 * __uint_as_float(v0.x << 16);
      a1 += al0 * __uint_as_float(v0.x & 0xFFFF0000u);
      a2 += al0 * __uint_as_float(v0.y << 16);
      a3 += al0 * __uint_as_float(v0.y & 0xFFFF0000u);
      a4 += al0 * __uint_as_float(v0.z << 16);
      a5 += al0 * __uint_as_float(v0.z & 0xFFFF0000u);
      a6 += al0 * __uint_as_float(v0.w << 16);
      a7 += al0 * __uint_as_float(v0.w & 0xFFFF0000u);
      a0 += al1 * __uint_as_float(v1.x << 16);
      a1 += al1 * __uint_as_float(v1.x & 0xFFFF0000u);
      a2 += al1 * __uint_as_float(v1.y << 16);
      a3 += al1 * __uint_as_float(v1.y & 0xFFFF0000u);
      a4 += al1 * __uint_as_float(v1.z << 16);
      a5 += al1 * __uint_as_float(v1.z & 0xFFFF0000u);
      a6 += al1 * __uint_as_float(v1.w << 16);
      a7 += al1 * __uint_as_float(v1.w & 0xFFFF0000u);
      a0 += al2 * __uint_as_float(v2.x << 16);
      a1 += al2 * __uint_as_float(v2.x & 0xFFFF0000u);
      a2 += al2 * __uint_as_float(v2.y << 16);
      a3 += al2 * __uint_as_float(v2.y & 0xFFFF0000u);
      a4 += al2 * __uint_as_float(v2.z << 16);
      a5 += al2 * __uint_as_float(v2.z & 0xFFFF0000u);
      a6 += al2 * __uint_as_float(v2.w << 16);
      a7 += al2 * __uint_as_float(v2.w & 0xFFFF0000u);
      a0 += al3 * __uint_as_float(v3.x << 16);
      a1 += al3 * __uint_as_float(v3.x & 0xFFFF0000u);
      a2 += al3 * __uint_as_float(v3.y << 16);
      a3 += al3 * __uint_as_float(v3.y & 0xFFFF0000u);
      a4 += al3 * __uint_as_float(v3.z << 16);
      a5 += al3 * __uint_as_float(v3.z & 0xFFFF0000u);
      a6 += al3 * __uint_as_float(v3.w << 16);
      a7 += al3 * __uint_as_float(v3.w & 0xFFFF0000u);
    }
    for (; e < cnt; e++) {
      float a = s_esc[g][e][h];
      int se = s_src[g][e];
      uint4 vv = *(const uint4*)(vb + (size_t)se*HD + s*8);
      a0 += a * __uint_as_float(vv.x << 16);
      a1 += a * __uint_as_float(vv.x & 0xFFFF0000u);
      a2 += a * __uint_as_float(vv.y << 16);
      a3 += a * __uint_as_float(vv.y & 0xFFFF0000u);
      a4 += a * __uint_as_float(vv.z << 16);
      a5 += a * __uint_as_float(vv.z & 0xFFFF0000u);
      a6 += a * __uint_as_float(vv.w << 16);
      a7 += a * __uint_as_float(vv.w & 0xFFFF0000u);
    }
    __builtin_amdgcn_wave_barrier();
  }
  #pragma unroll
  for (int off = 1; off < 16; off <<= 1) {
    dp0 += __shfl_xor(dp0, off);
    dp1 += __shfl_xor(dp1, off);
    dp2 += __shfl_xor(dp2, off);
    dp3 += __shfl_xor(dp3, off);
  }
  float den = (h == 0) ? dp0 : (h == 1) ? dp1 : (h == 2) ? dp2 : dp3;
  float inv = 1.f / (den + 1e-10f);
  uint4 pk;
  pk.x = (unsigned)f2bf(a0*inv) | ((unsigned)f2bf(a1*inv) << 16);
  pk.y = (unsigned)f2bf(a2*inv) | ((unsigned)f2bf(a3*inv) << 16);
  pk.z = (unsigned)f2bf(a4*inv) | ((unsigned)f2bf(a5*inv) << 16);
  pk.w = (unsigned)f2bf(a6*inv) | ((unsigned)f2bf(a7*inv) << 16);
  *(uint4*)orow = pk;
}

// ---------------- K4: MFMA GEMM  out = aggb @ Wout + bout ----------------
__global__ __launch_bounds__(256) void k4_gemm(const unsigned short* __restrict__ aggb,
    const uint4* __restrict__ Woutt, const float* __restrict__ bout,
    float* __restrict__ out, int n) {
  __shared__ uint4 ldsB[2048]; // 32KB
  int t = threadIdx.x;
  #pragma unroll
  for (int i = 0; i < 8; i++) ldsB[i*256 + t] = Woutt[i*256 + t];
  int wv = t >> 6, lane = t & 63;
  int l15 = lane & 15, l16 = lane >> 4;
  int base = blockIdx.x * 64;
  int arow = base + wv*16 + l15;
  int rr = min(arow, n - 1);
  const unsigned short* ar = &aggb[(size_t)rr*HD + l16*8];
  short8 afr[4];
  #pragma unroll
  for (int kk = 0; kk < 4; kk++)
    afr[kk] = *(const short8*)(ar + kk*32);
  __syncthreads();
  f32x4 acc[8];
  #pragma unroll
  for (int nt = 0; nt < 8; nt++) acc[nt] = (f32x4){0.f, 0.f, 0.f, 0.f};
  #pragma unroll
  for (int nt = 0; nt < 8; nt++) {
    int bcol = nt*16 + l15;
    #pragma unroll
    for (int kk = 0; kk < 4; kk++) {
      int bytec = kk*64 + l16*16;
      short8 b = *(const short8*)((const char*)ldsB + ((bcol*256 + bytec) ^ ((bcol & 7) << 4)));
      acc[nt] = __builtin_amdgcn_mfma_f32_16x16x32_bf16(afr[kk], b, acc[nt], 0, 0, 0);
    }
  }
  int rowbase = base + wv*16 + l16*4;
  #pragma unroll
  for (int nt = 0; nt < 8; nt++) {
    int col = nt*16 + l15;
    float bv = bout[col];
    #pragma unroll
    for (int r = 0; r < 4; r++) {
      int row = rowbase + r;
      if (row < n) out[(size_t)row*OUTD + col] = acc[nt][r] + bv;
    }
  }
}

extern "C" void kernel_launch(void* const* d_in, const int* in_sizes, int n_in,
                              void* d_out, int out_size, void* d_ws, size_t ws_size,
                              hipStream_t stream) {
  const float* x    = (const float*)d_in[0];
  const float* Wq   = (const float*)d_in[1];
  const float* Wk   = (const float*)d_in[2];
  const float* Wv   = (const float*)d_in[3];
  const float* attn = (const float*)d_in[4];
  const float* ee   = (const float*)d_in[5];
  const float* Wout = (const float*)d_in[6];
  const float* bout = (const float*)d_in[7];
  const int*   ei   = (const int*)d_in[8];
  const int*   et   = (const int*)d_in[9];
  int n  = in_sizes[0] / IND;
  int E_ = in_sizes[9];
  float* out = (float*)d_out;
  int nbuck = (n + 127) >> 7;

  char* w = (char*)d_ws;
  auto alloc = [&](size_t bytes) {
    char* p = w;
    w += (bytes + 255) & ~(size_t)255;
    return p;
  };
  unsigned short* vb    = (unsigned short*)alloc((size_t)n * HD * 2);
  unsigned short* aggb  = (unsigned short*)alloc((size_t)n * HD * 2);
  float* nq       = (float*)alloc((size_t)n * 16 * 4);
  float* skb      = (float*)alloc((size_t)n * 4 * 4);
  unsigned short* Wallt = (unsigned short*)alloc(160 * 128 * 2);
  unsigned short* Woutt = (unsigned short*)alloc(128 * 128 * 2);
  unsigned int* ebuf = (unsigned int*)alloc((size_t)nbuck * CAP * 4);
  int*   gbuck    = (int*)alloc((size_t)nbuck * 4);
  int*   offsets  = (int*)alloc(((size_t)n + 1) * 4);
  int*   elist    = (int*)alloc((size_t)E_ * 4);

  k0b_pack<<<289, 128, 0, stream>>>(Wq, Wk, attn, ee, Wv, Wout, Wallt, Woutt,
                                    gbuck, nbuck);
  k1_gemm<<<(n + 63)/64, 256, 0, stream>>>(x, (const uint4*)Wallt, vb, nq, skb, n);
  int nbb = 256;
  int per = (E_ + nbb - 1) / nbb;
  k_bucket<<<nbb, 256, 0, stream>>>(ei, et, gbuck, ebuf, E_, nbuck, per);
  k_sort<<<nbuck, 256, 0, stream>>>(ebuf, gbuck, offsets, elist, n, E_);
  k3_agg<<<(n + 15)/16, 256, 0, stream>>>(offsets, elist, nq, skb, vb, aggb, n);
  k4_gemm<<<(n + 63)/64, 256, 0, stream>>>(aggb, (const uint4*)Woutt, bout, out, n);
}

// Round 11
// 99.864 us; speedup vs baseline: 1.8505x; 1.0712x over previous
//
#include <hip/hip_runtime.h>
#include <hip/hip_bf16.h>

#define H_   4
#define D_   32
#define HD   128   // H*D
#define IND  128
#define OUTD 128
#define NET  3
#define NEG  0.2f
#define CAP  2048  // bucket capacity (expected ~819 edges/bucket, P(>2048) ~ 0)

typedef short short8 __attribute__((ext_vector_type(8)));
typedef float f32x4  __attribute__((ext_vector_type(4)));

__device__ __forceinline__ unsigned short f2bf(float f) {
  union { __hip_bfloat16 b; unsigned short u; } x;
  x.b = __float2bfloat16(f);
  return x.u;
}

__device__ __forceinline__ short8 pack_bf8(float4 lo, float4 hi) {
  union { short8 s; unsigned short u[8]; } r;
  r.u[0] = f2bf(lo.x); r.u[1] = f2bf(lo.y); r.u[2] = f2bf(lo.z); r.u[3] = f2bf(lo.w);
  r.u[4] = f2bf(hi.x); r.u[5] = f2bf(hi.y); r.u[6] = f2bf(hi.z); r.u[7] = f2bf(hi.w);
  return r.s;
}

#define BFLO(x) __uint_as_float((x) << 16)
#define BFHI(x) __uint_as_float((x) & 0xFFFF0000u)

// ---------------- K0b: pre-swizzled bf16 weight panels + inline Wred + gbuck zero ----------------
__global__ void k0b_pack(const float* __restrict__ Wq, const float* __restrict__ Wk,
                         const float* __restrict__ attn, const float* __restrict__ ee,
                         const float* __restrict__ Wv, const float* __restrict__ Wout,
                         unsigned short* __restrict__ Wallt,
                         unsigned short* __restrict__ Woutt,
                         int* __restrict__ gbuck, int nbuck) {
  int b = blockIdx.x, i = threadIdx.x; // i = K index
  if (b == 288) {
    for (int k = i; k < nbuck; k += 128) gbuck[k] = 0;  // replaces hipMemsetAsync
    return;
  }
  if (b < 160) {
    int c = b;
    float val = 0.f;
    if (c < 128) {
      val = Wv[i*HD + c];
    } else {
      int cc = c - 128;
      if (cc < 4) {                      // sq(h)
        int h = cc;
        for (int d = 0; d < D_; d++) val += Wq[i*HD + h*D_ + d] * attn[h*2*D_ + d];
      } else if (cc < 16) {              // qe(t,h)
        int t2 = (cc - 4) >> 2, h = (cc - 4) & 3;
        for (int d = 0; d < D_; d++) val += Wq[i*HD + h*D_ + d] * ee[t2*HD + h*D_ + d];
      } else if (cc < 20) {              // sk(h)
        int h = cc - 16;
        for (int d = 0; d < D_; d++) val += Wk[i*HD + h*D_ + d] * attn[h*2*D_ + D_ + d];
      }
    }
    Wallt[(c*128 + i) ^ ((c & 7) << 3)] = f2bf(val);
  } else {
    int c = b - 160;
    Woutt[(c*128 + i) ^ ((c & 7) << 3)] = f2bf(Wout[i*OUTD + c]);
  }
}

// ---------------- K1B: grid-split kernel — GEMM blocks + bucket blocks ----------------
// blocks [0, nblk1): MFMA GEMM x(n,128) @ [Wv|Wred](128,160); B panel in 40KB dyn LDS.
//   outputs: vb (bf16), nqb (bf16, 16/row: sq[4],qe[12]), skb (fp32, 4/row)
// blocks [nblk1, nblk1+256): edge bucketing by dst>>7 (LDS-privatized counters).
__global__ __launch_bounds__(256) void k1b(const float* __restrict__ x,
    const uint4* __restrict__ Wallt,
    unsigned short* __restrict__ vb, unsigned short* __restrict__ nqb,
    float* __restrict__ skb, int n, int nblk1,
    const int* __restrict__ ei, const int* __restrict__ et,
    int* __restrict__ gbuck, unsigned int* __restrict__ ebuf,
    int E_, int nbuck, int per) {
  extern __shared__ char dlds[];
  int t = threadIdx.x;
  if (blockIdx.x >= nblk1) {
    // ---- bucket part ----
    int* cnt  = (int*)dlds;
    int* base = cnt + 1024;
    for (int i = t; i < nbuck; i += 256) cnt[i] = 0;
    __syncthreads();
    int bb = blockIdx.x - nblk1;
    int e0 = bb * per;
    int e1 = min(e0 + per, E_);
    for (int e = e0 + t; e < e1; e += 256)
      atomicAdd(&cnt[ei[E_ + e] >> 7], 1);
    __syncthreads();
    for (int i = t; i < nbuck; i += 256) {
      int c = cnt[i];
      base[i] = c ? atomicAdd(&gbuck[i], c) : 0;
      cnt[i] = 0;
    }
    __syncthreads();
    for (int e = e0 + t; e < e1; e += 256) {
      int d = ei[E_ + e];
      int b = d >> 7;
      int pos = base[b] + atomicAdd(&cnt[b], 1);
      ebuf[(size_t)b * CAP + pos] =
          (unsigned)ei[e] | ((unsigned)et[e] << 17) | ((unsigned)(d & 127) << 19);
    }
    return;
  }
  // ---- GEMM part ----
  uint4* ldsB = (uint4*)dlds;
  #pragma unroll
  for (int i = 0; i < 10; i++) ldsB[i*256 + t] = Wallt[i*256 + t];
  int wv = t >> 6, lane = t & 63;
  int l15 = lane & 15, l16 = lane >> 4;
  int base = blockIdx.x * 64;
  int arow = base + wv*16 + l15;
  int rr = min(arow, n - 1);
  const float* xr = &x[(size_t)rr*IND + l16*8];
  short8 afr[4];
  #pragma unroll
  for (int kk = 0; kk < 4; kk++) {
    float4 lo = *(const float4*)(xr + kk*32);
    float4 hi = *(const float4*)(xr + kk*32 + 4);
    afr[kk] = pack_bf8(lo, hi);
  }
  __syncthreads();
  f32x4 acc[10];
  #pragma unroll
  for (int nt = 0; nt < 10; nt++) acc[nt] = (f32x4){0.f, 0.f, 0.f, 0.f};
  #pragma unroll
  for (int nt = 0; nt < 10; nt++) {
    int bcol = nt*16 + l15;
    #pragma unroll
    for (int kk = 0; kk < 4; kk++) {
      int bytec = kk*64 + l16*16;
      short8 b = *(const short8*)((const char*)ldsB + ((bcol*256 + bytec) ^ ((bcol & 7) << 4)));
      acc[nt] = __builtin_amdgcn_mfma_f32_16x16x32_bf16(afr[kk], b, acc[nt], 0, 0, 0);
    }
  }
  int rowbase = base + wv*16 + l16*4;
  #pragma unroll
  for (int nt = 0; nt < 10; nt++) {
    int col = nt*16 + l15;
    #pragma unroll
    for (int r = 0; r < 4; r++) {
      int row = rowbase + r;
      if (row >= n) continue;
      float val = acc[nt][r];
      if (nt < 8)       vb[(size_t)row*HD + col] = f2bf(val);
      else if (nt == 8) nqb[((size_t)row << 4) + (col - 128)] = f2bf(val);
      else { int c = col - 144; if (c < 4) skb[(size_t)row*4 + c] = val; }
    }
  }
}

// per-bucket counting sort; computes its own bucket base from gbuck (bscan folded in)
__global__ __launch_bounds__(256) void k_sort(const unsigned int* __restrict__ ebuf,
    const int* __restrict__ gbuck, int* __restrict__ offsets,
    int* __restrict__ elist, int n, int E_) {
  __shared__ int cnt[128], cur[128], sc[128], red[256];
  int b = blockIdx.x, t = threadIdx.x;
  int part = 0;
  for (int i = t; i < b; i += 256) part += gbuck[i];
  red[t] = part; __syncthreads();
  for (int off = 128; off > 0; off >>= 1) {
    if (t < off) red[t] += red[t + off];
    __syncthreads();
  }
  int bb = red[0];
  int m = gbuck[b];
  if (b == 0 && t == 0) offsets[n] = E_;
  if (t < 128) cnt[t] = 0;
  __syncthreads();
  const unsigned int* eb = ebuf + (size_t)b * CAP;
  for (int i = t; i < m; i += 256)
    atomicAdd(&cnt[(eb[i] >> 19) & 127], 1);
  __syncthreads();
  if (t < 128) sc[t] = cnt[t];
  __syncthreads();
  for (int off = 1; off < 128; off <<= 1) {
    int v = (t >= off && t < 128) ? sc[t - off] : 0;
    __syncthreads();
    if (t < 128) sc[t] += v;
    __syncthreads();
  }
  if (t < 128) {
    int excl = sc[t] - cnt[t];
    cur[t] = excl;
    int dst = b * 128 + t;
    if (dst < n) offsets[dst] = bb + excl;
  }
  __syncthreads();
  for (int i = t; i < m; i += 256) {
    unsigned int w = eb[i];
    int dl = (w >> 19) & 127;
    int p = bb + atomicAdd(&cur[dl], 1);
    elist[p] = (int)((w & 0x1FFFFu) | (((w >> 17) & 3u) << 20));
  }
}

// ---------------- K3: 16-lane-group-per-dst softmax + aggregation, bf16 in/out ----------------
// No max-shift: scores ~N(0,3.4), exp(s) safe in fp32; alpha identical to ref to ~1e-10.
__global__ __launch_bounds__(256) void k3_agg(
    const int* __restrict__ offsets, const int* __restrict__ elist,
    const unsigned short* __restrict__ nqb, const float* __restrict__ skb,
    const unsigned short* __restrict__ vb, unsigned short* __restrict__ aggb, int n) {
  int t = threadIdx.x;
  int g = t >> 4, s = t & 15;
  int dst = blockIdx.x * 16 + g;
  __shared__ float s_esc[16][17][4];   // [17]: group bank offsets distinct -> no conflicts
  __shared__ int s_src[16][17];        // holds src*HD (vb element offset)
  if (dst >= n) return;
  int off0 = offsets[dst];
  int deg = offsets[dst + 1] - off0;
  int h = s >> 2;                       // head of my 8 dims [s*8 .. s*8+8)
  unsigned short* orow = &aggb[(size_t)dst*HD + s*8];
  if (deg == 0) {
    *(uint4*)orow = make_uint4(0u, 0u, 0u, 0u);
    return;
  }
  float4 sk4 = *(const float4*)(&skb[(size_t)dst*4]);
  float dp0 = 0.f, dp1 = 0.f, dp2 = 0.f, dp3 = 0.f;
  float a0=0.f,a1=0.f,a2=0.f,a3=0.f,a4=0.f,a5=0.f,a6=0.f,a7=0.f;
  for (int bas = 0; bas < deg; bas += 16) {
    int cnt = min(16, deg - bas);
    float e0 = 0.f, e1 = 0.f, e2 = 0.f, e3 = 0.f;
    int srcoff = 0;
    if (s < cnt) {
      int p = elist[off0 + bas + s];
      int src = p & 0xFFFFF;
      int ety = p >> 20;
      const unsigned short* nr = nqb + ((size_t)src << 4);
      uint2 sqp = *(const uint2*)nr;                 // sq[0..3] bf16
      uint2 qep = *(const uint2*)(nr + 4 + ety*4);   // qe[ety][0..3] bf16
      float s0 = BFLO(sqp.x) + sk4.x;
      float s1 = BFHI(sqp.x) + sk4.y;
      float s2 = BFLO(sqp.y) + sk4.z;
      float s3 = BFHI(sqp.y) + sk4.w;
      s0 = (s0 >= 0.f ? s0 : NEG*s0) + BFLO(qep.x); e0 = __expf(s0);
      s1 = (s1 >= 0.f ? s1 : NEG*s1) + BFHI(qep.x); e1 = __expf(s1);
      s2 = (s2 >= 0.f ? s2 : NEG*s2) + BFLO(qep.y); e2 = __expf(s2);
      s3 = (s3 >= 0.f ? s3 : NEG*s3) + BFHI(qep.y); e3 = __expf(s3);
      dp0 += e0; dp1 += e1; dp2 += e2; dp3 += e3;
      srcoff = src << 7;               // src*HD
    }
    s_src[g][s] = srcoff;
    *(float4*)(&s_esc[g][s][0]) = make_float4(e0, e1, e2, e3);
    __builtin_amdgcn_wave_barrier();
    int e = 0;
    for (; e + 4 <= cnt; e += 4) {       // 4 gathers in flight per lane
      float al0 = s_esc[g][e+0][h], al1 = s_esc[g][e+1][h];
      float al2 = s_esc[g][e+2][h], al3 = s_esc[g][e+3][h];
      const unsigned short* p0 = vb + s_src[g][e+0] + s*8;
      const unsigned short* p1 = vb + s_src[g][e+1] + s*8;
      const unsigned short* p2 = vb + s_src[g][e+2] + s*8;
      const unsigned short* p3 = vb + s_src[g][e+3] + s*8;
      uint4 v0 = *(const uint4*)p0;
      uint4 v1 = *(const uint4*)p1;
      uint4 v2 = *(const uint4*)p2;
      uint4 v3 = *(const uint4*)p3;
      a0 += al0 * BFLO(v0.x); a1 += al0 * BFHI(v0.x);
      a2 += al0 * BFLO(v0.y); a3 += al0 * BFHI(v0.y);
      a4 += al0 * BFLO(v0.z); a5 += al0 * BFHI(v0.z);
      a6 += al0 * BFLO(v0.w); a7 += al0 * BFHI(v0.w);
      a0 += al1 * BFLO(v1.x); a1 += al1 * BFHI(v1.x);
      a2 += al1 * BFLO(v1.y); a3 += al1 * BFHI(v1.y);
      a4 += al1 * BFLO(v1.z); a5 += al1 * BFHI(v1.z);
      a6 += al1 * BFLO(v1.w); a7 += al1 * BFHI(v1.w);
      a0 += al2 * BFLO(v2.x); a1 += al2 * BFHI(v2.x);
      a2 += al2 * BFLO(v2.y); a3 += al2 * BFHI(v2.y);
      a4 += al2 * BFLO(v2.z); a5 += al2 * BFHI(v2.z);
      a6 += al2 * BFLO(v2.w); a7 += al2 * BFHI(v2.w);
      a0 += al3 * BFLO(v3.x); a1 += al3 * BFHI(v3.x);
      a2 += al3 * BFLO(v3.y); a3 += al3 * BFHI(v3.y);
      a4 += al3 * BFLO(v3.z); a5 += al3 * BFHI(v3.z);
      a6 += al3 * BFLO(v3.w); a7 += al3 * BFHI(v3.w);
    }
    for (; e < cnt; e++) {
      float a = s_esc[g][e][h];
      const unsigned short* p = vb + s_src[g][e] + s*8;
      uint4 vv = *(const uint4*)p;
      a0 += a * BFLO(vv.x); a1 += a * BFHI(vv.x);
      a2 += a * BFLO(vv.y); a3 += a * BFHI(vv.y);
      a4 += a * BFLO(vv.z); a5 += a * BFHI(vv.z);
      a6 += a * BFLO(vv.w); a7 += a * BFHI(vv.w);
    }
    __builtin_amdgcn_wave_barrier();
  }
  #pragma unroll
  for (int off = 1; off < 16; off <<= 1) {
    dp0 += __shfl_xor(dp0, off);
    dp1 += __shfl_xor(dp1, off);
    dp2 += __shfl_xor(dp2, off);
    dp3 += __shfl_xor(dp3, off);
  }
  float den = (h == 0) ? dp0 : (h == 1) ? dp1 : (h == 2) ? dp2 : dp3;
  float inv = 1.f / (den + 1e-10f);
  uint4 pk;
  pk.x = (unsigned)f2bf(a0*inv) | ((unsigned)f2bf(a1*inv) << 16);
  pk.y = (unsigned)f2bf(a2*inv) | ((unsigned)f2bf(a3*inv) << 16);
  pk.z = (unsigned)f2bf(a4*inv) | ((unsigned)f2bf(a5*inv) << 16);
  pk.w = (unsigned)f2bf(a6*inv) | ((unsigned)f2bf(a7*inv) << 16);
  *(uint4*)orow = pk;
}

// ---------------- K4: MFMA GEMM  out = aggb @ Wout + bout ----------------
__global__ __launch_bounds__(256) void k4_gemm(const unsigned short* __restrict__ aggb,
    const uint4* __restrict__ Woutt, const float* __restrict__ bout,
    float* __restrict__ out, int n) {
  __shared__ uint4 ldsB[2048]; // 32KB
  int t = threadIdx.x;
  #pragma unroll
  for (int i = 0; i < 8; i++) ldsB[i*256 + t] = Woutt[i*256 + t];
  int wv = t >> 6, lane = t & 63;
  int l15 = lane & 15, l16 = lane >> 4;
  int base = blockIdx.x * 64;
  int arow = base + wv*16 + l15;
  int rr = min(arow, n - 1);
  const unsigned short* ar = &aggb[(size_t)rr*HD + l16*8];
  short8 afr[4];
  #pragma unroll
  for (int kk = 0; kk < 4; kk++)
    afr[kk] = *(const short8*)(ar + kk*32);
  __syncthreads();
  f32x4 acc[8];
  #pragma unroll
  for (int nt = 0; nt < 8; nt++) acc[nt] = (f32x4){0.f, 0.f, 0.f, 0.f};
  #pragma unroll
  for (int nt = 0; nt < 8; nt++) {
    int bcol = nt*16 + l15;
    #pragma unroll
    for (int kk = 0; kk < 4; kk++) {
      int bytec = kk*64 + l16*16;
      short8 b = *(const short8*)((const char*)ldsB + ((bcol*256 + bytec) ^ ((bcol & 7) << 4)));
      acc[nt] = __builtin_amdgcn_mfma_f32_16x16x32_bf16(afr[kk], b, acc[nt], 0, 0, 0);
    }
  }
  int rowbase = base + wv*16 + l16*4;
  #pragma unroll
  for (int nt = 0; nt < 8; nt++) {
    int col = nt*16 + l15;
    float bv = bout[col];
    #pragma unroll
    for (int r = 0; r < 4; r++) {
      int row = rowbase + r;
      if (row < n) out[(size_t)row*OUTD + col] = acc[nt][r] + bv;
    }
  }
}

extern "C" void kernel_launch(void* const* d_in, const int* in_sizes, int n_in,
                              void* d_out, int out_size, void* d_ws, size_t ws_size,
                              hipStream_t stream) {
  const float* x    = (const float*)d_in[0];
  const float* Wq   = (const float*)d_in[1];
  const float* Wk   = (const float*)d_in[2];
  const float* Wv   = (const float*)d_in[3];
  const float* attn = (const float*)d_in[4];
  const float* ee   = (const float*)d_in[5];
  const float* Wout = (const float*)d_in[6];
  const float* bout = (const float*)d_in[7];
  const int*   ei   = (const int*)d_in[8];
  const int*   et   = (const int*)d_in[9];
  int n  = in_sizes[0] / IND;
  int E_ = in_sizes[9];
  float* out = (float*)d_out;
  int nbuck = (n + 127) >> 7;

  char* w = (char*)d_ws;
  auto alloc = [&](size_t bytes) {
    char* p = w;
    w += (bytes + 255) & ~(size_t)255;
    return p;
  };
  unsigned short* vb    = (unsigned short*)alloc((size_t)n * HD * 2);
  unsigned short* aggb  = (unsigned short*)alloc((size_t)n * HD * 2);
  unsigned short* nqb   = (unsigned short*)alloc((size_t)n * 16 * 2);
  float* skb      = (float*)alloc((size_t)n * 4 * 4);
  unsigned short* Wallt = (unsigned short*)alloc(160 * 128 * 2);
  unsigned short* Woutt = (unsigned short*)alloc(128 * 128 * 2);
  unsigned int* ebuf = (unsigned int*)alloc((size_t)nbuck * CAP * 4);
  int*   gbuck    = (int*)alloc((size_t)nbuck * 4);
  int*   offsets  = (int*)alloc(((size_t)n + 1) * 4);
  int*   elist    = (int*)alloc((size_t)E_ * 4);

  k0b_pack<<<289, 128, 0, stream>>>(Wq, Wk, attn, ee, Wv, Wout, Wallt, Woutt,
                                    gbuck, nbuck);
  int nblk1 = (n + 63) / 64;
  int nbb = 256;
  int per = (E_ + nbb - 1) / nbb;
  k1b<<<nblk1 + nbb, 256, 40960, stream>>>(x, (const uint4*)Wallt, vb, nqb, skb,
                                           n, nblk1, ei, et, gbuck, ebuf,
                                           E_, nbuck, per);
  k_sort<<<nbuck, 256, 0, stream>>>(ebuf, gbuck, offsets, elist, n, E_);
  k3_agg<<<(n + 15)/16, 256, 0, stream>>>(offsets, elist, nqb, skb, vb, aggb, n);
  k4_gemm<<<(n + 63)/64, 256, 0, stream>>>(aggb, (const uint4*)Woutt, bout, out, n);
}